// Round 13
// baseline (560.676 us; speedup 1.0000x reference)
//
#include <hip/hip_runtime.h>
#include <hip/hip_bf16.h>

#define VN    64
#define KPAD  264   // bf16 row stride: rows 16B-aligned (528B)

typedef __bf16 bf16x8 __attribute__((ext_vector_type(8)));
typedef __bf16 bf16x2 __attribute__((ext_vector_type(2)));
typedef float  f32x4  __attribute__((ext_vector_type(4)));

// packed-weight bf16 element offsets in d_ws
#define OFF_W0   0
#define OFF_SK0  40960
#define OFF_W1   81920
#define OFF_SK1  147456
#define OFF_W2   212992
#define OFF_SK2  278528
#define OFF_W3   344064
#define OFF_H1W  409600
#define OFF_SA0  475136    // score cols layer0: 160 x 16
#define OFF_SA1  477696    // 256 x 16
#define OFF_SA2  481792
#define OFF_SA3  485888
#define OFF_END  489984    // bf16 elems; byte 979968 (16B aligned)

// ---- one fused setup kernel: weight pack + h2W transpose + score cols + temb
// blocks 0..1855 pack, 1856..1857 h2wt, 1858..1915 sa_pack, 1916..2939 temb(x2)
__global__ void setup_all(const float* __restrict__ W0s, const float* __restrict__ sk0s,
                          const float* __restrict__ W1s, const float* __restrict__ sk1s,
                          const float* __restrict__ W2s, const float* __restrict__ sk2s,
                          const float* __restrict__ W3s, const float* __restrict__ h1Ws,
                          const float* __restrict__ h2W,
                          const float* __restrict__ as0, const float* __restrict__ at0,
                          const float* __restrict__ as1, const float* __restrict__ at1,
                          const float* __restrict__ as2, const float* __restrict__ at2,
                          const float* __restrict__ as3, const float* __restrict__ at3,
                          const int* __restrict__ t, const float* __restrict__ tW,
                          const float* __restrict__ tb,
                          float* __restrict__ h2wt, float* __restrict__ d_temb,
                          __bf16* __restrict__ wp)
{
  int blk = blockIdx.x, tid = threadIdx.x;
  if (blk < 1856) {
    const float* src; int fin, dstoff, rel;
    if (blk < 320) {
      if (blk < 160) { src = W0s;  dstoff = OFF_W0;  rel = blk; }
      else           { src = sk0s; dstoff = OFF_SK0; rel = blk - 160; }
      fin = 134;
    } else {
      int r = (blk - 320) >> 8;
      rel = (blk - 320) & 255;
      const float* srcs[6] = {W1s, sk1s, W2s, sk2s, W3s, h1Ws};
      const int    offs[6] = {OFF_W1, OFF_SK1, OFF_W2, OFF_SK2, OFF_W3, OFF_H1W};
      src = srcs[r]; dstoff = offs[r]; fin = 256;
    }
    int idx = rel * 256 + tid;
    int rr = idx & 7, n = (idx >> 3) & 255, c = idx >> 11;
    int k = c * 8 + rr;
    float v = (k < fin) ? src[k * 256 + n] : 0.0f;
    wp[dstoff + idx] = (__bf16)v;
  } else if (blk < 1858) {
    int idx = (blk - 1856) * 256 + tid;
    int c = idx >> 8, k = idx & 255;
    h2wt[idx] = h2W[k * 2 + c];
  } else if (blk < 1916) {
    int idx = (blk - 1858) * 256 + tid;   // 928 rows x 16 cols = 14848
    if (idx < 14848) {
      int gk = idx >> 4, c = idx & 15;
      int li, k, fin, dstoff;
      if (gk < 160)      { li = 0; k = gk;       fin = 134; dstoff = OFF_SA0; }
      else if (gk < 416) { li = 1; k = gk - 160; fin = 256; dstoff = OFF_SA1; }
      else if (gk < 672) { li = 2; k = gk - 416; fin = 256; dstoff = OFF_SA2; }
      else               { li = 3; k = gk - 672; fin = 256; dstoff = OFF_SA3; }
      float v = 0.0f;
      if (k < fin) {
        if (li < 3) {
          if (c < 8) {
            int hd = c & 3;
            const float* Wm = (li == 0) ? W0s : (li == 1) ? W1s : W2s;
            const float* a  = (c < 4) ? ((li == 0) ? as0 : (li == 1) ? as1 : as2)
                                      : ((li == 0) ? at0 : (li == 1) ? at1 : at2);
            for (int f = 0; f < 64; f++)
              v += Wm[k * 256 + hd * 64 + f] * a[hd * 64 + f];
          }
        } else {
          if (c < 2) {
            const float* a = (c == 0) ? as3 : at3;
            for (int f = 0; f < 256; f++)
              v += W3s[k * 256 + f] * a[f];
          }
        }
      }
      wp[dstoff + ((k >> 3) * 16 + c) * 8 + (k & 7)] = (__bf16)v;
    }
  } else {
    // temb: 2 polygons per block, 128 threads each
    __shared__ float se[2][128];
    int half = tid >> 7, tt = tid & 127;
    int b = (blk - 1916) * 2 + half;
    int fi = tt & 63;
    float fr = expf(-logf(10000.0f) * (float)fi / 63.0f);
    float te = (float)t[b] * fr;
    se[half][tt] = (tt < 64) ? sinf(te) : cosf(te);
    __syncthreads();
    float a = tb[tt];
    for (int k = 0; k < 128; k++)
      a = fmaf(se[half][k], tW[k * 128 + tt], a);
    d_temb[b * 128 + tt] = a / (1.0f + expf(-a));
  }
}

// single-B matmul: acc += A(64 x 32*KS from LDS) @ B(packed global)
template<int KS>
__device__ __forceinline__ void mfma_mm(const __bf16* __restrict__ Bp,
                                        f32x4 acc[4][4],
                                        const __bf16* __restrict__ shA,
                                        int l, int q, int colbase8)
{
#pragma unroll
  for (int s = 0; s < KS; s++) {
    bf16x8 af[4], bfr[4];
#pragma unroll
    for (int rt = 0; rt < 4; rt++)
      af[rt] = *(const bf16x8*)(shA + (rt * 16 + l) * KPAD + s * 32 + q * 8);
#pragma unroll
    for (int ct = 0; ct < 4; ct++)
      bfr[ct] = *(const bf16x8*)(Bp + (s * 4 + q) * 2048 + colbase8 + ct * 128);
#pragma unroll
    for (int rt = 0; rt < 4; rt++)
#pragma unroll
      for (int ct = 0; ct < 4; ct++)
        acc[rt][ct] = __builtin_amdgcn_mfma_f32_16x16x32_bf16(af[rt], bfr[ct], acc[rt][ct], 0, 0, 0);
  }
}

// matmul + score columns: acc += A@B, acc_sc += A@SA (16-col packed)
template<int KS>
__device__ __forceinline__ void mfma_mm_sc(const __bf16* __restrict__ Bp,
                                           const __bf16* __restrict__ SAp,
                                           f32x4 acc[4][4], f32x4 acc_sc[4],
                                           const __bf16* __restrict__ shA,
                                           int l, int q, int colbase8)
{
#pragma unroll
  for (int s = 0; s < KS; s++) {
    bf16x8 af[4], bfr[4], bsc;
#pragma unroll
    for (int rt = 0; rt < 4; rt++)
      af[rt] = *(const bf16x8*)(shA + (rt * 16 + l) * KPAD + s * 32 + q * 8);
#pragma unroll
    for (int ct = 0; ct < 4; ct++)
      bfr[ct] = *(const bf16x8*)(Bp + (s * 4 + q) * 2048 + colbase8 + ct * 128);
    bsc = *(const bf16x8*)(SAp + (s * 4 + q) * 128 + l * 8);
#pragma unroll
    for (int rt = 0; rt < 4; rt++) {
#pragma unroll
      for (int ct = 0; ct < 4; ct++)
        acc[rt][ct] = __builtin_amdgcn_mfma_f32_16x16x32_bf16(af[rt], bfr[ct], acc[rt][ct], 0, 0, 0);
      acc_sc[rt] = __builtin_amdgcn_mfma_f32_16x16x32_bf16(af[rt], bsc, acc_sc[rt], 0, 0, 0);
    }
  }
}

__global__ __launch_bounds__(256, 1)   // r13: 512-reg budget, no spills; LDS caps blocks/CU
void gat_poly_kernel(const float* __restrict__ x,
                     const float* __restrict__ b0, const float* __restrict__ b1,
                     const float* __restrict__ b2, const float* __restrict__ b3,
                     const float* __restrict__ h1b, const float* __restrict__ h2b,
                     const __bf16* __restrict__ WP,
                     const float* __restrict__ h2wt,
                     const float* __restrict__ d_temb,
                     float* __restrict__ out)
{
  __shared__ __bf16 bufA[VN * KPAD];
  __shared__ __bf16 bufB[VN * KPAD];
  __shared__ float  sh_temb[128];
  __shared__ float  sh_ssp[VN * 4];      // s_src [n][head]
  __shared__ float  sh_stp[VN * 4];      // s_tgt [n][head]
  __shared__ float  sh_al[VN][4][3];     // alphas [n][head][edge]

  const int b    = blockIdx.x;
  const int tid  = threadIdx.x;
  const int w    = tid >> 6;
  const int lane = tid & 63;
  const int l    = lane & 15;
  const int q    = lane >> 4;
  const int cb   = w * 64;
  const int colbase8 = (cb + l) * 8;

  // flat-epilogue indexing: f-pair + node half
  const int fp = (tid & 127) * 2;
  const int nb = (tid >> 7) * 32;
  const int fhd = fp >> 6;

  __bf16* hb = bufA;   // current activations (MFMA A source)
  __bf16* ag = bufB;   // skip+bias staging / proj buffer

  if (tid < 128) sh_temb[tid] = d_temb[b * 128 + tid];
  __syncthreads();

  // ------------- h0 = [coords(2), pos(4), temb(128)], zero pad to 160 --------
  for (int idx = tid; idx < VN * 160; idx += 256) {
    int n = idx / 160, k = idx - n * 160;
    float v = 0.0f;
    if (k < 2) {
      v = x[b * 128 + 2 * n + k];
    } else if (k < 6) {
      float ph  = (float)n * 0.09817477042468103f;  // 2*pi/64
      float arg = (k < 4) ? ph : 2.0f * ph;
      v = ((k & 1) == 0) ? sinf(arg) : cosf(arg);
    } else if (k < 134) {
      v = sh_temb[k - 6];
    }
    hb[n * KPAD + k] = (__bf16)v;
  }
  __syncthreads();

  const int WOFFS[3]  = {OFF_W0, OFF_W1, OFF_W2};
  const int SOFFS[3]  = {OFF_SK0, OFF_SK1, OFF_SK2};
  const int SAOFFS[3] = {OFF_SA0, OFF_SA1, OFF_SA2};
  const float* Bs[3]  = {b0, b1, b2};

  // ---------------- GAT layers 0..2 (NH=4, FOUT=64, concat + elu) ------------
  for (int li = 0; li < 3; li++) {
    // ---- pass A: skip projection + bias -> ag (bf16, lane-owned) ----
    {
      f32x4 accS[4][4];
#pragma unroll
      for (int rt = 0; rt < 4; rt++)
#pragma unroll
        for (int ct = 0; ct < 4; ct++) accS[rt][ct] = (f32x4)0.0f;
      if (li == 0) mfma_mm<5>(WP + OFF_SK0,   accS, hb, l, q, colbase8);
      else         mfma_mm<8>(WP + SOFFS[li], accS, hb, l, q, colbase8);
      float b4[4];
#pragma unroll
      for (int ct = 0; ct < 4; ct++) b4[ct] = Bs[li][cb + ct * 16 + l];
#pragma unroll
      for (int rt = 0; rt < 4; rt++)
#pragma unroll
        for (int reg = 0; reg < 4; reg++) {
          int n = rt * 16 + q * 4 + reg;
#pragma unroll
          for (int ct = 0; ct < 4; ct++)
            ag[n * KPAD + cb + ct * 16 + l] = (__bf16)(accS[rt][ct][reg] + b4[ct]);
        }
    }

    // ---- pass B: main projection + score columns ----
    f32x4 acc[4][4], acc_sc[4];
#pragma unroll
    for (int rt = 0; rt < 4; rt++) {
#pragma unroll
      for (int ct = 0; ct < 4; ct++) acc[rt][ct] = (f32x4)0.0f;
      acc_sc[rt] = (f32x4)0.0f;
    }
    if (li == 0) mfma_mm_sc<5>(WP + OFF_W0,    WP + OFF_SA0,    acc, acc_sc, hb, l, q, colbase8);
    else         mfma_mm_sc<8>(WP + WOFFS[li], WP + SAOFFS[li], acc, acc_sc, hb, l, q, colbase8);

    // scores -> LDS: col l<4 = s_src head l, col 4..7 = s_tgt (r10-proven)
    if (l < 8) {
#pragma unroll
      for (int rt = 0; rt < 4; rt++)
#pragma unroll
        for (int reg = 0; reg < 4; reg++) {
          int n = rt * 16 + q * 4 + reg;
          float v = acc_sc[rt][reg];
          if (l < 4) sh_ssp[n * 4 + l] = v;
          else       sh_stp[n * 4 + (l - 4)] = v;
        }
    }
    __syncthreads();   // all hb reads done (A+B); scores visible

    // proj dump: acc -> hb (bf16, lane-owned; h is dead now)
#pragma unroll
    for (int rt = 0; rt < 4; rt++)
#pragma unroll
      for (int reg = 0; reg < 4; reg++) {
        int n = rt * 16 + q * 4 + reg;
#pragma unroll
        for (int ct = 0; ct < 4; ct++)
          hb[n * KPAD + cb + ct * 16 + l] = (__bf16)acc[rt][ct][reg];
      }

    { // softmax over {prv,nxt,self}: thread per (node, head) — proven r2 form
      int n = tid >> 2, hd = tid & 3;
      int prv = (n + 63) & 63, nxt = (n + 1) & 63;
      float stg = sh_stp[n * 4 + hd];
      float e0 = sh_ssp[prv * 4 + hd] + stg; e0 = (e0 < 0.0f) ? 0.2f * e0 : e0;
      float e1 = sh_ssp[nxt * 4 + hd] + stg; e1 = (e1 < 0.0f) ? 0.2f * e1 : e1;
      float e2 = sh_ssp[n * 4 + hd]   + stg; e2 = (e2 < 0.0f) ? 0.2f * e2 : e2;
      float mx = fmaxf(e0, fmaxf(e1, e2));
      float x0 = expf(e0 - mx), x1 = expf(e1 - mx), x2 = expf(e2 - mx);
      float inv = 1.0f / (x0 + x1 + x2 + 1e-16f);
      sh_al[n][hd][0] = x0 * inv;
      sh_al[n][hd][1] = x1 * inv;
      sh_al[n][hd][2] = x2 * inv;
    }
    __syncthreads();   // proj + alphas visible

    // ---- flat epilogue: o = elu(a0*proj[prv]+a1*proj[nxt]+a2*proj[n] + ag)
    //      thread owns f-pair fp, nodes nb..nb+31; lane-private RMW on ag ----
    {
      float pm0, pm1, pc0, pc1;
      { bf16x2 v = *(const bf16x2*)(hb + ((nb + 63) & 63) * KPAD + fp); pm0 = v[0]; pm1 = v[1]; }
      { bf16x2 v = *(const bf16x2*)(hb + nb * KPAD + fp);               pc0 = v[0]; pc1 = v[1]; }
#pragma unroll 8
      for (int i = 0; i < 32; i++) {
        int n = nb + i;
        bf16x2 pnv = *(const bf16x2*)(hb + ((n + 1) & 63) * KPAD + fp);
        bf16x2 agv = *(const bf16x2*)(ag + n * KPAD + fp);
        float a0 = sh_al[n][fhd][0], a1 = sh_al[n][fhd][1], a2 = sh_al[n][fhd][2];
        float o0 = a0 * pm0 + a1 * (float)pnv[0] + a2 * pc0 + (float)agv[0];
        float o1 = a0 * pm1 + a1 * (float)pnv[1] + a2 * pc1 + (float)agv[1];
        o0 = (o0 > 0.0f) ? o0 : (expf(o0) - 1.0f);
        o1 = (o1 > 0.0f) ? o1 : (expf(o1) - 1.0f);
        bf16x2 ov; ov[0] = (__bf16)o0; ov[1] = (__bf16)o1;
        *(bf16x2*)(ag + n * KPAD + fp) = ov;
        pm0 = pc0; pm1 = pc1; pc0 = (float)pnv[0]; pc1 = (float)pnv[1];
      }
    }
    __syncthreads();   // new h (in ag) complete

    __bf16* tmp = hb; hb = ag; ag = tmp;   // ping-pong
  }

  // ---------------- GAT layer 3 (NH=1, FOUT=256, identity skip, no act) ------
  {
    f32x4 acc[4][4], acc_sc[4];
#pragma unroll
    for (int rt = 0; rt < 4; rt++) {
#pragma unroll
      for (int ct = 0; ct < 4; ct++) acc[rt][ct] = (f32x4)0.0f;
      acc_sc[rt] = (f32x4)0.0f;
    }
    mfma_mm_sc<8>(WP + OFF_W3, WP + OFF_SA3, acc, acc_sc, hb, l, q, colbase8);

    if (l < 2) {   // col 0 = s_src, col 1 = s_tgt
#pragma unroll
      for (int rt = 0; rt < 4; rt++)
#pragma unroll
        for (int reg = 0; reg < 4; reg++) {
          int n = rt * 16 + q * 4 + reg;
          float v = acc_sc[rt][reg];
          if (l == 0) sh_ssp[n * 4] = v;
          else        sh_stp[n * 4] = v;
        }
    }
    __syncthreads();

    // proj dump: acc -> ag (hb holds h, needed for residual)
#pragma unroll
    for (int rt = 0; rt < 4; rt++)
#pragma unroll
      for (int reg = 0; reg < 4; reg++) {
        int n = rt * 16 + q * 4 + reg;
#pragma unroll
        for (int ct = 0; ct < 4; ct++)
          ag[n * KPAD + cb + ct * 16 + l] = (__bf16)acc[rt][ct][reg];
      }

    if (tid < 64) {  // softmax, single head
      int n = tid;
      float ssn = sh_ssp[n * 4];
      float stn = sh_stp[n * 4];
      float ssp = __shfl(ssn, (n + 63) & 63, 64);
      float ssx = __shfl(ssn, (n + 1) & 63, 64);
      float e0 = ssp + stn; e0 = (e0 < 0.0f) ? 0.2f * e0 : e0;
      float e1 = ssx + stn; e1 = (e1 < 0.0f) ? 0.2f * e1 : e1;
      float e2 = ssn + stn; e2 = (e2 < 0.0f) ? 0.2f * e2 : e2;
      float mx = fmaxf(e0, fmaxf(e1, e2));
      float x0 = expf(e0 - mx), x1 = expf(e1 - mx), x2 = expf(e2 - mx);
      float inv = 1.0f / (x0 + x1 + x2 + 1e-16f);
      sh_al[n][0][0] = x0 * inv;
      sh_al[n][0][1] = x1 * inv;
      sh_al[n][0][2] = x2 * inv;
    }
    __syncthreads();

    { // flat epilogue: o = gather(ag) + hb(residual) + b3 -> hb (lane-private RMW)
      float b30 = b3[fp], b31 = b3[fp + 1];
      float pm0, pm1, pc0, pc1;
      { bf16x2 v = *(const bf16x2*)(ag + ((nb + 63) & 63) * KPAD + fp); pm0 = v[0]; pm1 = v[1]; }
      { bf16x2 v = *(const bf16x2*)(ag + nb * KPAD + fp);               pc0 = v[0]; pc1 = v[1]; }
#pragma unroll 8
      for (int i = 0; i < 32; i++) {
        int n = nb + i;
        bf16x2 pnv = *(const bf16x2*)(ag + ((n + 1) & 63) * KPAD + fp);
        bf16x2 hrv = *(const bf16x2*)(hb + n * KPAD + fp);
        float a0 = sh_al[n][0][0], a1 = sh_al[n][0][1], a2 = sh_al[n][0][2];
        float o0 = a0 * pm0 + a1 * (float)pnv[0] + a2 * pc0 + (float)hrv[0] + b30;
        float o1 = a0 * pm1 + a1 * (float)pnv[1] + a2 * pc1 + (float)hrv[1] + b31;
        bf16x2 ov; ov[0] = (__bf16)o0; ov[1] = (__bf16)o1;
        *(bf16x2*)(hb + n * KPAD + fp) = ov;
        pm0 = pc0; pm1 = pc1; pc0 = (float)pnv[0]; pc1 = (float)pnv[1];
      }
    }
    __syncthreads();
  }

  // ---------------- head MLP: silu(h@h1W+h1b), then h@h2W+h2b ----------------
  {
    f32x4 acc[4][4];
#pragma unroll
    for (int rt = 0; rt < 4; rt++)
#pragma unroll
      for (int ct = 0; ct < 4; ct++) acc[rt][ct] = (f32x4)0.0f;
    mfma_mm<8>(WP + OFF_H1W, acc, hb, l, q, colbase8);
    __syncthreads();

    float b4[4];
#pragma unroll
    for (int ct = 0; ct < 4; ct++) b4[ct] = h1b[cb + ct * 16 + l];
#pragma unroll
    for (int rt = 0; rt < 4; rt++)
#pragma unroll
      for (int reg = 0; reg < 4; reg++) {
        int n = rt * 16 + q * 4 + reg;
#pragma unroll
        for (int ct = 0; ct < 4; ct++) {
          float o = acc[rt][ct][reg] + b4[ct];
          o = o / (1.0f + expf(-o));
          hb[n * KPAD + cb + ct * 16 + l] = (__bf16)o;
        }
      }
    __syncthreads();

    { // final 256 -> 2, all 256 threads: split-K by 2 + pair combine
      int n = tid >> 2, c = (tid >> 1) & 1, half = tid & 1;
      const float* wrow = h2wt + c * 256 + half * 128;
      const __bf16* hrow = hb + n * KPAD + half * 128;
      float o = half ? 0.0f : h2b[c];
#pragma unroll 4
      for (int k8 = 0; k8 < 16; k8++) {
        bf16x8 hv = *(const bf16x8*)(hrow + k8 * 8);
        f32x4 w0 = *(const f32x4*)(wrow + k8 * 8);
        f32x4 w1 = *(const f32x4*)(wrow + k8 * 8 + 4);
#pragma unroll
        for (int j = 0; j < 4; j++) o = fmaf((float)hv[j], w0[j], o);
#pragma unroll
        for (int j = 0; j < 4; j++) o = fmaf((float)hv[4 + j], w1[j], o);
      }
      o += __shfl_xor(o, 1, 64);
      if (!half) out[b * 128 + 2 * n + c] = o;
    }
  }
}

extern "C" void kernel_launch(void* const* d_in, const int* in_sizes, int n_in,
                              void* d_out, int out_size, void* d_ws, size_t ws_size,
                              hipStream_t stream)
{
  auto fp = [&](int i) { return (const float*)d_in[i]; };
  __bf16* wp   = (__bf16*)d_ws;
  float* h2wt  = (float*)(wp + OFF_END);        // 512 fp32 (16B aligned)
  float* dtemb = h2wt + 512;                    // 2048*128 fp32

  setup_all<<<2940, 256, 0, stream>>>(fp(4), fp(20), fp(8), fp(21),
                                      fp(12), fp(22), fp(16), fp(23),
                                      fp(25),
                                      fp(5),  fp(6),  fp(9),  fp(10),
                                      fp(13), fp(14), fp(17), fp(18),
                                      (const int*)d_in[1], fp(2), fp(3),
                                      h2wt, dtemb, wp);

  gat_poly_kernel<<<2048, 256, 0, stream>>>(
      fp(0),
      fp(7), fp(11), fp(15), fp(19),   // b0..b3
      fp(24), fp(26),                  // h1b h2b
      wp, h2wt, dtemb,
      (float*)d_out);
}

// Round 14
// 520.506 us; speedup vs baseline: 1.0772x; 1.0772x over previous
//
#include <hip/hip_runtime.h>
#include <hip/hip_bf16.h>

#define VN    64
#define KPAD  264   // bf16 row stride: rows 16B-aligned (528B)

typedef __bf16 bf16x8 __attribute__((ext_vector_type(8)));
typedef __bf16 bf16x2 __attribute__((ext_vector_type(2)));
typedef float  f32x4  __attribute__((ext_vector_type(4)));

// packed-weight bf16 element offsets in d_ws
#define OFF_W0   0
#define OFF_SK0  40960
#define OFF_W1   81920
#define OFF_SK1  147456
#define OFF_W2   212992
#define OFF_SK2  278528
#define OFF_W3   344064
#define OFF_H1W  409600
#define OFF_SA0  475136    // score cols layer0: 160 x 16
#define OFF_SA1  477696    // 256 x 16
#define OFF_SA2  481792
#define OFF_SA3  485888
#define OFF_END  489984    // bf16 elems; byte 979968 (16B aligned)

// ---- one fused setup kernel (unchanged from r11/r12) ----
__global__ void setup_all(const float* __restrict__ W0s, const float* __restrict__ sk0s,
                          const float* __restrict__ W1s, const float* __restrict__ sk1s,
                          const float* __restrict__ W2s, const float* __restrict__ sk2s,
                          const float* __restrict__ W3s, const float* __restrict__ h1Ws,
                          const float* __restrict__ h2W,
                          const float* __restrict__ as0, const float* __restrict__ at0,
                          const float* __restrict__ as1, const float* __restrict__ at1,
                          const float* __restrict__ as2, const float* __restrict__ at2,
                          const float* __restrict__ as3, const float* __restrict__ at3,
                          const int* __restrict__ t, const float* __restrict__ tW,
                          const float* __restrict__ tb,
                          float* __restrict__ h2wt, float* __restrict__ d_temb,
                          __bf16* __restrict__ wp)
{
  int blk = blockIdx.x, tid = threadIdx.x;
  if (blk < 1856) {
    const float* src; int fin, dstoff, rel;
    if (blk < 320) {
      if (blk < 160) { src = W0s;  dstoff = OFF_W0;  rel = blk; }
      else           { src = sk0s; dstoff = OFF_SK0; rel = blk - 160; }
      fin = 134;
    } else {
      int r = (blk - 320) >> 8;
      rel = (blk - 320) & 255;
      const float* srcs[6] = {W1s, sk1s, W2s, sk2s, W3s, h1Ws};
      const int    offs[6] = {OFF_W1, OFF_SK1, OFF_W2, OFF_SK2, OFF_W3, OFF_H1W};
      src = srcs[r]; dstoff = offs[r]; fin = 256;
    }
    int idx = rel * 256 + tid;
    int rr = idx & 7, n = (idx >> 3) & 255, c = idx >> 11;
    int k = c * 8 + rr;
    float v = (k < fin) ? src[k * 256 + n] : 0.0f;
    wp[dstoff + idx] = (__bf16)v;
  } else if (blk < 1858) {
    int idx = (blk - 1856) * 256 + tid;
    int c = idx >> 8, k = idx & 255;
    h2wt[idx] = h2W[k * 2 + c];
  } else if (blk < 1916) {
    int idx = (blk - 1858) * 256 + tid;   // 928 rows x 16 cols = 14848
    if (idx < 14848) {
      int gk = idx >> 4, c = idx & 15;
      int li, k, fin, dstoff;
      if (gk < 160)      { li = 0; k = gk;       fin = 134; dstoff = OFF_SA0; }
      else if (gk < 416) { li = 1; k = gk - 160; fin = 256; dstoff = OFF_SA1; }
      else if (gk < 672) { li = 2; k = gk - 416; fin = 256; dstoff = OFF_SA2; }
      else               { li = 3; k = gk - 672; fin = 256; dstoff = OFF_SA3; }
      float v = 0.0f;
      if (k < fin) {
        if (li < 3) {
          if (c < 8) {
            int hd = c & 3;
            const float* Wm = (li == 0) ? W0s : (li == 1) ? W1s : W2s;
            const float* a  = (c < 4) ? ((li == 0) ? as0 : (li == 1) ? as1 : as2)
                                      : ((li == 0) ? at0 : (li == 1) ? at1 : at2);
            for (int f = 0; f < 64; f++)
              v += Wm[k * 256 + hd * 64 + f] * a[hd * 64 + f];
          }
        } else {
          if (c < 2) {
            const float* a = (c == 0) ? as3 : at3;
            for (int f = 0; f < 256; f++)
              v += W3s[k * 256 + f] * a[f];
          }
        }
      }
      wp[dstoff + ((k >> 3) * 16 + c) * 8 + (k & 7)] = (__bf16)v;
    }
  } else {
    // temb: 2 polygons per block, 128 threads each
    __shared__ float se[2][128];
    int half = tid >> 7, tt = tid & 127;
    int b = (blk - 1916) * 2 + half;
    int fi = tt & 63;
    float fr = expf(-logf(10000.0f) * (float)fi / 63.0f);
    float te = (float)t[b] * fr;
    se[half][tt] = (tt < 64) ? sinf(te) : cosf(te);
    __syncthreads();
    float a = tb[tt];
    for (int k = 0; k < 128; k++)
      a = fmaf(se[half][k], tW[k * 128 + tt], a);
    d_temb[b * 128 + tt] = a / (1.0f + expf(-a));
  }
}

// 4x4 matmul: acc += A(64 x 32*KS from LDS) @ B(packed global), 64 cols
template<int KS>
__device__ __forceinline__ void mfma_mm(const __bf16* __restrict__ Bp,
                                        f32x4 acc[4][4],
                                        const __bf16* __restrict__ shA,
                                        int l, int q, int colbase8)
{
#pragma unroll
  for (int s = 0; s < KS; s++) {
    bf16x8 af[4], bfr[4];
#pragma unroll
    for (int rt = 0; rt < 4; rt++)
      af[rt] = *(const bf16x8*)(shA + (rt * 16 + l) * KPAD + s * 32 + q * 8);
#pragma unroll
    for (int ct = 0; ct < 4; ct++)
      bfr[ct] = *(const bf16x8*)(Bp + (s * 4 + q) * 2048 + colbase8 + ct * 128);
#pragma unroll
    for (int rt = 0; rt < 4; rt++)
#pragma unroll
      for (int ct = 0; ct < 4; ct++)
        acc[rt][ct] = __builtin_amdgcn_mfma_f32_16x16x32_bf16(af[rt], bfr[ct], acc[rt][ct], 0, 0, 0);
  }
}

// 4x4 matmul + 16-col score columns
template<int KS>
__device__ __forceinline__ void mfma_mm_sc(const __bf16* __restrict__ Bp,
                                           const __bf16* __restrict__ SAp,
                                           f32x4 acc[4][4], f32x4 acc_sc[4],
                                           const __bf16* __restrict__ shA,
                                           int l, int q, int colbase8)
{
#pragma unroll
  for (int s = 0; s < KS; s++) {
    bf16x8 af[4], bfr[4], bsc;
#pragma unroll
    for (int rt = 0; rt < 4; rt++)
      af[rt] = *(const bf16x8*)(shA + (rt * 16 + l) * KPAD + s * 32 + q * 8);
#pragma unroll
    for (int ct = 0; ct < 4; ct++)
      bfr[ct] = *(const bf16x8*)(Bp + (s * 4 + q) * 2048 + colbase8 + ct * 128);
    bsc = *(const bf16x8*)(SAp + (s * 4 + q) * 128 + l * 8);
#pragma unroll
    for (int rt = 0; rt < 4; rt++) {
#pragma unroll
      for (int ct = 0; ct < 4; ct++)
        acc[rt][ct] = __builtin_amdgcn_mfma_f32_16x16x32_bf16(af[rt], bfr[ct], acc[rt][ct], 0, 0, 0);
      acc_sc[rt] = __builtin_amdgcn_mfma_f32_16x16x32_bf16(af[rt], bsc, acc_sc[rt], 0, 0, 0);
    }
  }
}

// 4x2 matmul: 32 cols per wave (layer 3 / h1W, 8-wave split)
template<int KS>
__device__ __forceinline__ void mfma_mm2(const __bf16* __restrict__ Bp,
                                         f32x4 acc[4][2],
                                         const __bf16* __restrict__ shA,
                                         int l, int q, int colbase8)
{
#pragma unroll
  for (int s = 0; s < KS; s++) {
    bf16x8 af[4], bfr[2];
#pragma unroll
    for (int rt = 0; rt < 4; rt++)
      af[rt] = *(const bf16x8*)(shA + (rt * 16 + l) * KPAD + s * 32 + q * 8);
#pragma unroll
    for (int ct = 0; ct < 2; ct++)
      bfr[ct] = *(const bf16x8*)(Bp + (s * 4 + q) * 2048 + colbase8 + ct * 128);
#pragma unroll
    for (int rt = 0; rt < 4; rt++)
#pragma unroll
      for (int ct = 0; ct < 2; ct++)
        acc[rt][ct] = __builtin_amdgcn_mfma_f32_16x16x32_bf16(af[rt], bfr[ct], acc[rt][ct], 0, 0, 0);
  }
}

// 4x2 matmul + score columns (wave 0, layer 3)
template<int KS>
__device__ __forceinline__ void mfma_mm2_sc(const __bf16* __restrict__ Bp,
                                            const __bf16* __restrict__ SAp,
                                            f32x4 acc[4][2], f32x4 acc_sc[4],
                                            const __bf16* __restrict__ shA,
                                            int l, int q, int colbase8)
{
#pragma unroll
  for (int s = 0; s < KS; s++) {
    bf16x8 af[4], bfr[2], bsc;
#pragma unroll
    for (int rt = 0; rt < 4; rt++)
      af[rt] = *(const bf16x8*)(shA + (rt * 16 + l) * KPAD + s * 32 + q * 8);
#pragma unroll
    for (int ct = 0; ct < 2; ct++)
      bfr[ct] = *(const bf16x8*)(Bp + (s * 4 + q) * 2048 + colbase8 + ct * 128);
    bsc = *(const bf16x8*)(SAp + (s * 4 + q) * 128 + l * 8);
#pragma unroll
    for (int rt = 0; rt < 4; rt++) {
#pragma unroll
      for (int ct = 0; ct < 2; ct++)
        acc[rt][ct] = __builtin_amdgcn_mfma_f32_16x16x32_bf16(af[rt], bfr[ct], acc[rt][ct], 0, 0, 0);
      acc_sc[rt] = __builtin_amdgcn_mfma_f32_16x16x32_bf16(af[rt], bsc, acc_sc[rt], 0, 0, 0);
    }
  }
}

__global__ __launch_bounds__(512, 2)   // 8 waves/block, 256-reg budget/wave
void gat_poly_kernel(const float* __restrict__ x,
                     const float* __restrict__ b0, const float* __restrict__ b1,
                     const float* __restrict__ b2, const float* __restrict__ b3,
                     const float* __restrict__ h1b, const float* __restrict__ h2b,
                     const __bf16* __restrict__ WP,
                     const float* __restrict__ h2wt,
                     const float* __restrict__ d_temb,
                     float* __restrict__ out)
{
  __shared__ __bf16 bufA[VN * KPAD];
  __shared__ __bf16 bufB[VN * KPAD];
  __shared__ float  sh_temb[128];
  __shared__ float  sh_ssp[VN * 4];      // s_src [n][head]
  __shared__ float  sh_stp[VN * 4];      // s_tgt [n][head]
  __shared__ float  sh_al[VN][4][3];     // alphas [n][head][edge]

  const int b    = blockIdx.x;
  const int tid  = threadIdx.x;
  const int wid  = tid >> 6;            // 0..7
  const int lane = tid & 63;
  const int l    = lane & 15;
  const int q    = lane >> 4;
  const int w4   = wid & 3;             // head / col group within W or skip
  const bool isW = (wid < 4);
  const int cb   = w4 * 64;             // layers 0-2 col base (per matrix)
  const int colbase8   = (cb + l) * 8;
  const int cb2  = wid * 32;            // layer3/h1W col base (8-way split)
  const int colbase8_2 = (cb2 + l) * 8;

  // flat-epilogue indexing: f-pair + 16-node stripe
  const int fp  = (tid & 127) * 2;
  const int nq  = (tid >> 7) * 16;
  const int fhd = fp >> 6;

  __bf16* hb = bufA;   // current activations (MFMA A source)
  __bf16* ag = bufB;   // skip+bias staging / proj buffer

  if (tid < 128) sh_temb[tid] = d_temb[b * 128 + tid];
  __syncthreads();

  // ------------- h0 = [coords(2), pos(4), temb(128)], zero pad to 160 --------
  for (int idx = tid; idx < VN * 160; idx += 512) {
    int n = idx / 160, k = idx - n * 160;
    float v = 0.0f;
    if (k < 2) {
      v = x[b * 128 + 2 * n + k];
    } else if (k < 6) {
      float ph  = (float)n * 0.09817477042468103f;  // 2*pi/64
      float arg = (k < 4) ? ph : 2.0f * ph;
      v = ((k & 1) == 0) ? sinf(arg) : cosf(arg);
    } else if (k < 134) {
      v = sh_temb[k - 6];
    }
    hb[n * KPAD + k] = (__bf16)v;
  }
  __syncthreads();

  const int WOFFS[3]  = {OFF_W0, OFF_W1, OFF_W2};
  const int SOFFS[3]  = {OFF_SK0, OFF_SK1, OFF_SK2};
  const int SAOFFS[3] = {OFF_SA0, OFF_SA1, OFF_SA2};
  const float* Bs[3]  = {b0, b1, b2};

  // ---------------- GAT layers 0..2 (NH=4, FOUT=64, concat + elu) ------------
  // waves 0-3: h@W (+ scores on wave 0) ; waves 4-7: h@skip + bias -> ag
  for (int li = 0; li < 3; li++) {
    f32x4 acc[4][4];
#pragma unroll
    for (int rt = 0; rt < 4; rt++)
#pragma unroll
      for (int ct = 0; ct < 4; ct++) acc[rt][ct] = (f32x4)0.0f;

    if (wid == 0) {
      f32x4 acc_sc[4];
#pragma unroll
      for (int rt = 0; rt < 4; rt++) acc_sc[rt] = (f32x4)0.0f;
      if (li == 0) mfma_mm_sc<5>(WP + OFF_W0,    WP + OFF_SA0,    acc, acc_sc, hb, l, q, colbase8);
      else         mfma_mm_sc<8>(WP + WOFFS[li], WP + SAOFFS[li], acc, acc_sc, hb, l, q, colbase8);
      if (l < 8) {   // col l<4 = s_src head l, 4..7 = s_tgt head l-4
#pragma unroll
        for (int rt = 0; rt < 4; rt++)
#pragma unroll
          for (int reg = 0; reg < 4; reg++) {
            int n = rt * 16 + q * 4 + reg;
            float v = acc_sc[rt][reg];
            if (l < 4) sh_ssp[n * 4 + l] = v;
            else       sh_stp[n * 4 + (l - 4)] = v;
          }
      }
    } else if (isW) {
      if (li == 0) mfma_mm<5>(WP + OFF_W0,    acc, hb, l, q, colbase8);
      else         mfma_mm<8>(WP + WOFFS[li], acc, hb, l, q, colbase8);
    } else {
      if (li == 0) mfma_mm<5>(WP + OFF_SK0,   acc, hb, l, q, colbase8);
      else         mfma_mm<8>(WP + SOFFS[li], acc, hb, l, q, colbase8);
      // ag = skip + bias (lane-owned; ag not read by anyone yet)
      float b4[4];
#pragma unroll
      for (int ct = 0; ct < 4; ct++) b4[ct] = Bs[li][cb + ct * 16 + l];
#pragma unroll
      for (int rt = 0; rt < 4; rt++)
#pragma unroll
        for (int reg = 0; reg < 4; reg++) {
          int n = rt * 16 + q * 4 + reg;
#pragma unroll
          for (int ct = 0; ct < 4; ct++)
            ag[n * KPAD + cb + ct * 16 + l] = (__bf16)(acc[rt][ct][reg] + b4[ct]);
        }
    }
    __syncthreads();   // all hb reads done; scores + ag visible

    if (isW) {   // proj dump: acc -> hb (h is dead now)
#pragma unroll
      for (int rt = 0; rt < 4; rt++)
#pragma unroll
        for (int reg = 0; reg < 4; reg++) {
          int n = rt * 16 + q * 4 + reg;
#pragma unroll
          for (int ct = 0; ct < 4; ct++)
            hb[n * KPAD + cb + ct * 16 + l] = (__bf16)acc[rt][ct][reg];
        }
    } else {     // waves 4-7: softmax, thread per (node, head)
      int tt = tid - 256, n = tt >> 2, hd = tt & 3;
      int prv = (n + 63) & 63, nxt = (n + 1) & 63;
      float stg = sh_stp[n * 4 + hd];
      float e0 = sh_ssp[prv * 4 + hd] + stg; e0 = (e0 < 0.0f) ? 0.2f * e0 : e0;
      float e1 = sh_ssp[nxt * 4 + hd] + stg; e1 = (e1 < 0.0f) ? 0.2f * e1 : e1;
      float e2 = sh_ssp[n * 4 + hd]   + stg; e2 = (e2 < 0.0f) ? 0.2f * e2 : e2;
      float mx = fmaxf(e0, fmaxf(e1, e2));
      float x0 = expf(e0 - mx), x1 = expf(e1 - mx), x2 = expf(e2 - mx);
      float inv = 1.0f / (x0 + x1 + x2 + 1e-16f);
      sh_al[n][hd][0] = x0 * inv;
      sh_al[n][hd][1] = x1 * inv;
      sh_al[n][hd][2] = x2 * inv;
    }
    __syncthreads();   // proj + alphas visible

    // ---- flat epilogue: o = elu(a0*proj[prv]+a1*proj[nxt]+a2*proj[n] + ag)
    //      thread owns f-pair fp, 16-node stripe nq..nq+15 ----
    {
      float pm0, pm1, pc0, pc1;
      { bf16x2 v = *(const bf16x2*)(hb + ((nq + 63) & 63) * KPAD + fp); pm0 = v[0]; pm1 = v[1]; }
      { bf16x2 v = *(const bf16x2*)(hb + nq * KPAD + fp);               pc0 = v[0]; pc1 = v[1]; }
#pragma unroll 8
      for (int i = 0; i < 16; i++) {
        int n = nq + i;
        bf16x2 pnv = *(const bf16x2*)(hb + ((n + 1) & 63) * KPAD + fp);
        bf16x2 agv = *(const bf16x2*)(ag + n * KPAD + fp);
        float a0 = sh_al[n][fhd][0], a1 = sh_al[n][fhd][1], a2 = sh_al[n][fhd][2];
        float o0 = a0 * pm0 + a1 * (float)pnv[0] + a2 * pc0 + (float)agv[0];
        float o1 = a0 * pm1 + a1 * (float)pnv[1] + a2 * pc1 + (float)agv[1];
        o0 = (o0 > 0.0f) ? o0 : (expf(o0) - 1.0f);
        o1 = (o1 > 0.0f) ? o1 : (expf(o1) - 1.0f);
        bf16x2 ov; ov[0] = (__bf16)o0; ov[1] = (__bf16)o1;
        *(bf16x2*)(ag + n * KPAD + fp) = ov;
        pm0 = pc0; pm1 = pc1; pc0 = (float)pnv[0]; pc1 = (float)pnv[1];
      }
    }
    __syncthreads();   // new h (in ag) complete

    __bf16* tmp = hb; hb = ag; ag = tmp;   // ping-pong
  }

  // ---------------- GAT layer 3 (NH=1, FOUT=256, identity skip, no act) ------
  // 8 waves x 32 cols of W3 (4x2 tiles); wave 0 carries the 2 score cols
  {
    f32x4 acc[4][2];
#pragma unroll
    for (int rt = 0; rt < 4; rt++)
#pragma unroll
      for (int ct = 0; ct < 2; ct++) acc[rt][ct] = (f32x4)0.0f;

    if (wid == 0) {
      f32x4 acc_sc[4];
#pragma unroll
      for (int rt = 0; rt < 4; rt++) acc_sc[rt] = (f32x4)0.0f;
      mfma_mm2_sc<8>(WP + OFF_W3, WP + OFF_SA3, acc, acc_sc, hb, l, q, colbase8_2);
      if (l < 2) {   // col 0 = s_src, col 1 = s_tgt
#pragma unroll
        for (int rt = 0; rt < 4; rt++)
#pragma unroll
          for (int reg = 0; reg < 4; reg++) {
            int n = rt * 16 + q * 4 + reg;
            float v = acc_sc[rt][reg];
            if (l == 0) sh_ssp[n * 4] = v;
            else        sh_stp[n * 4] = v;
          }
      }
    } else {
      mfma_mm2<8>(WP + OFF_W3, acc, hb, l, q, colbase8_2);
    }

    // proj dump -> ag (hb holds h for the residual; ag is dead)
#pragma unroll
    for (int rt = 0; rt < 4; rt++)
#pragma unroll
      for (int reg = 0; reg < 4; reg++) {
        int n = rt * 16 + q * 4 + reg;
#pragma unroll
        for (int ct = 0; ct < 2; ct++)
          ag[n * KPAD + cb2 + ct * 16 + l] = (__bf16)acc[rt][ct][reg];
      }
    __syncthreads();   // scores + proj visible; hb reads done

    if (tid >= 256 && tid < 320) {  // wave 4: softmax, single head
      int n = tid - 256;
      float ssn = sh_ssp[n * 4];
      float stn = sh_stp[n * 4];
      float ssp = __shfl(ssn, (n + 63) & 63, 64);
      float ssx = __shfl(ssn, (n + 1) & 63, 64);
      float e0 = ssp + stn; e0 = (e0 < 0.0f) ? 0.2f * e0 : e0;
      float e1 = ssx + stn; e1 = (e1 < 0.0f) ? 0.2f * e1 : e1;
      float e2 = ssn + stn; e2 = (e2 < 0.0f) ? 0.2f * e2 : e2;
      float mx = fmaxf(e0, fmaxf(e1, e2));
      float x0 = expf(e0 - mx), x1 = expf(e1 - mx), x2 = expf(e2 - mx);
      float inv = 1.0f / (x0 + x1 + x2 + 1e-16f);
      sh_al[n][0][0] = x0 * inv;
      sh_al[n][0][1] = x1 * inv;
      sh_al[n][0][2] = x2 * inv;
    }
    __syncthreads();

    { // flat epilogue: o = gather(ag) + hb(residual) + b3 -> hb
      float b30 = b3[fp], b31 = b3[fp + 1];
      float pm0, pm1, pc0, pc1;
      { bf16x2 v = *(const bf16x2*)(ag + ((nq + 63) & 63) * KPAD + fp); pm0 = v[0]; pm1 = v[1]; }
      { bf16x2 v = *(const bf16x2*)(ag + nq * KPAD + fp);               pc0 = v[0]; pc1 = v[1]; }
#pragma unroll 8
      for (int i = 0; i < 16; i++) {
        int n = nq + i;
        bf16x2 pnv = *(const bf16x2*)(ag + ((n + 1) & 63) * KPAD + fp);
        bf16x2 hrv = *(const bf16x2*)(hb + n * KPAD + fp);
        float a0 = sh_al[n][0][0], a1 = sh_al[n][0][1], a2 = sh_al[n][0][2];
        float o0 = a0 * pm0 + a1 * (float)pnv[0] + a2 * pc0 + (float)hrv[0] + b30;
        float o1 = a0 * pm1 + a1 * (float)pnv[1] + a2 * pc1 + (float)hrv[1] + b31;
        bf16x2 ov; ov[0] = (__bf16)o0; ov[1] = (__bf16)o1;
        *(bf16x2*)(hb + n * KPAD + fp) = ov;
        pm0 = pc0; pm1 = pc1; pc0 = (float)pnv[0]; pc1 = (float)pnv[1];
      }
    }
    __syncthreads();
  }

  // ---------------- head MLP: silu(h@h1W+h1b) -> ag, then ag@h2W+h2b ---------
  {
    f32x4 acc[4][2];
#pragma unroll
    for (int rt = 0; rt < 4; rt++)
#pragma unroll
      for (int ct = 0; ct < 2; ct++) acc[rt][ct] = (f32x4)0.0f;
    mfma_mm2<8>(WP + OFF_H1W, acc, hb, l, q, colbase8_2);

    float b2r[2];
#pragma unroll
    for (int ct = 0; ct < 2; ct++) b2r[ct] = h1b[cb2 + ct * 16 + l];
#pragma unroll
    for (int rt = 0; rt < 4; rt++)
#pragma unroll
      for (int reg = 0; reg < 4; reg++) {
        int n = rt * 16 + q * 4 + reg;
#pragma unroll
        for (int ct = 0; ct < 2; ct++) {
          float o = acc[rt][ct][reg] + b2r[ct];
          o = o / (1.0f + expf(-o));
          ag[n * KPAD + cb2 + ct * 16 + l] = (__bf16)o;  // write to ag: hb stays intact
        }
      }
    __syncthreads();

    { // final 256 -> 2, 512 threads: split-K by 4 + combine
      int n = tid >> 3, c = (tid >> 2) & 1, qtr = tid & 3;
      const float* wrow = h2wt + c * 256 + qtr * 64;
      const __bf16* hrow = ag + n * KPAD + qtr * 64;
      float o = (qtr == 0) ? h2b[c] : 0.0f;
#pragma unroll
      for (int k8 = 0; k8 < 8; k8++) {
        bf16x8 hv = *(const bf16x8*)(hrow + k8 * 8);
        f32x4 w0 = *(const f32x4*)(wrow + k8 * 8);
        f32x4 w1 = *(const f32x4*)(wrow + k8 * 8 + 4);
#pragma unroll
        for (int j = 0; j < 4; j++) o = fmaf((float)hv[j], w0[j], o);
#pragma unroll
        for (int j = 0; j < 4; j++) o = fmaf((float)hv[4 + j], w1[j], o);
      }
      o += __shfl_xor(o, 1, 64);
      o += __shfl_xor(o, 2, 64);
      if (qtr == 0) out[b * 128 + 2 * n + c] = o;
    }
  }
}

extern "C" void kernel_launch(void* const* d_in, const int* in_sizes, int n_in,
                              void* d_out, int out_size, void* d_ws, size_t ws_size,
                              hipStream_t stream)
{
  auto fp = [&](int i) { return (const float*)d_in[i]; };
  __bf16* wp   = (__bf16*)d_ws;
  float* h2wt  = (float*)(wp + OFF_END);        // 512 fp32 (16B aligned)
  float* dtemb = h2wt + 512;                    // 2048*128 fp32

  setup_all<<<2940, 256, 0, stream>>>(fp(4), fp(20), fp(8), fp(21),
                                      fp(12), fp(22), fp(16), fp(23),
                                      fp(25),
                                      fp(5),  fp(6),  fp(9),  fp(10),
                                      fp(13), fp(14), fp(17), fp(18),
                                      (const int*)d_in[1], fp(2), fp(3),
                                      h2wt, dtemb, wp);

  gat_poly_kernel<<<2048, 512, 0, stream>>>(
      fp(0),
      fp(7), fp(11), fp(15), fp(19),   // b0..b3
      fp(24), fp(26),                  // h1b h2b
      wp, h2wt, dtemb,
      (float*)d_out);
}

// Round 15
// 428.187 us; speedup vs baseline: 1.3094x; 1.2156x over previous
//
#include <hip/hip_runtime.h>
#include <hip/hip_bf16.h>

#define VN    64
#define KPAD  264   // bf16 row stride: rows 16B-aligned (528B)

typedef __bf16 bf16x8 __attribute__((ext_vector_type(8)));
typedef __bf16 bf16x2 __attribute__((ext_vector_type(2)));
typedef float  f32x4  __attribute__((ext_vector_type(4)));

// packed-weight bf16 element offsets in d_ws
#define OFF_W0   0
#define OFF_SK0  40960
#define OFF_W1   81920
#define OFF_SK1  147456
#define OFF_W2   212992
#define OFF_SK2  278528
#define OFF_W3   344064
#define OFF_H1W  409600
#define OFF_SA0  475136    // score cols layer0: 160 x 16
#define OFF_SA1  477696    // 256 x 16
#define OFF_SA2  481792
#define OFF_SA3  485888
#define OFF_END  489984    // bf16 elems; byte 979968 (16B aligned)

// ---- one fused setup kernel (unchanged from r11) ----
__global__ void setup_all(const float* __restrict__ W0s, const float* __restrict__ sk0s,
                          const float* __restrict__ W1s, const float* __restrict__ sk1s,
                          const float* __restrict__ W2s, const float* __restrict__ sk2s,
                          const float* __restrict__ W3s, const float* __restrict__ h1Ws,
                          const float* __restrict__ h2W,
                          const float* __restrict__ as0, const float* __restrict__ at0,
                          const float* __restrict__ as1, const float* __restrict__ at1,
                          const float* __restrict__ as2, const float* __restrict__ at2,
                          const float* __restrict__ as3, const float* __restrict__ at3,
                          const int* __restrict__ t, const float* __restrict__ tW,
                          const float* __restrict__ tb,
                          float* __restrict__ h2wt, float* __restrict__ d_temb,
                          __bf16* __restrict__ wp)
{
  int blk = blockIdx.x, tid = threadIdx.x;
  if (blk < 1856) {
    const float* src; int fin, dstoff, rel;
    if (blk < 320) {
      if (blk < 160) { src = W0s;  dstoff = OFF_W0;  rel = blk; }
      else           { src = sk0s; dstoff = OFF_SK0; rel = blk - 160; }
      fin = 134;
    } else {
      int r = (blk - 320) >> 8;
      rel = (blk - 320) & 255;
      const float* srcs[6] = {W1s, sk1s, W2s, sk2s, W3s, h1Ws};
      const int    offs[6] = {OFF_W1, OFF_SK1, OFF_W2, OFF_SK2, OFF_W3, OFF_H1W};
      src = srcs[r]; dstoff = offs[r]; fin = 256;
    }
    int idx = rel * 256 + tid;
    int rr = idx & 7, n = (idx >> 3) & 255, c = idx >> 11;
    int k = c * 8 + rr;
    float v = (k < fin) ? src[k * 256 + n] : 0.0f;
    wp[dstoff + idx] = (__bf16)v;
  } else if (blk < 1858) {
    int idx = (blk - 1856) * 256 + tid;
    int c = idx >> 8, k = idx & 255;
    h2wt[idx] = h2W[k * 2 + c];
  } else if (blk < 1916) {
    int idx = (blk - 1858) * 256 + tid;   // 928 rows x 16 cols = 14848
    if (idx < 14848) {
      int gk = idx >> 4, c = idx & 15;
      int li, k, fin, dstoff;
      if (gk < 160)      { li = 0; k = gk;       fin = 134; dstoff = OFF_SA0; }
      else if (gk < 416) { li = 1; k = gk - 160; fin = 256; dstoff = OFF_SA1; }
      else if (gk < 672) { li = 2; k = gk - 416; fin = 256; dstoff = OFF_SA2; }
      else               { li = 3; k = gk - 672; fin = 256; dstoff = OFF_SA3; }
      float v = 0.0f;
      if (k < fin) {
        if (li < 3) {
          if (c < 8) {
            int hd = c & 3;
            const float* Wm = (li == 0) ? W0s : (li == 1) ? W1s : W2s;
            const float* a  = (c < 4) ? ((li == 0) ? as0 : (li == 1) ? as1 : as2)
                                      : ((li == 0) ? at0 : (li == 1) ? at1 : at2);
            for (int f = 0; f < 64; f++)
              v += Wm[k * 256 + hd * 64 + f] * a[hd * 64 + f];
          }
        } else {
          if (c < 2) {
            const float* a = (c == 0) ? as3 : at3;
            for (int f = 0; f < 256; f++)
              v += W3s[k * 256 + f] * a[f];
          }
        }
      }
      wp[dstoff + ((k >> 3) * 16 + c) * 8 + (k & 7)] = (__bf16)v;
    }
  } else {
    // temb: 2 polygons per block, 128 threads each
    __shared__ float se[2][128];
    int half = tid >> 7, tt = tid & 127;
    int b = (blk - 1916) * 2 + half;
    int fi = tt & 63;
    float fr = expf(-logf(10000.0f) * (float)fi / 63.0f);
    float te = (float)t[b] * fr;
    se[half][tt] = (tt < 64) ? sinf(te) : cosf(te);
    __syncthreads();
    float a = tb[tt];
    for (int k = 0; k < 128; k++)
      a = fmaf(se[half][k], tW[k * 128 + tt], a);
    d_temb[b * 128 + tt] = a / (1.0f + expf(-a));
  }
}

// single-B matmul, af loaded per-rt (lower fragment register pressure)
template<int KS>
__device__ __forceinline__ void mfma_mm(const __bf16* __restrict__ Bp,
                                        f32x4 acc[4][4],
                                        const __bf16* __restrict__ shA,
                                        int l, int q, int colbase8)
{
#pragma unroll
  for (int s = 0; s < KS; s++) {
    bf16x8 bfr[4];
#pragma unroll
    for (int ct = 0; ct < 4; ct++)
      bfr[ct] = *(const bf16x8*)(Bp + (s * 4 + q) * 2048 + colbase8 + ct * 128);
#pragma unroll
    for (int rt = 0; rt < 4; rt++) {
      bf16x8 af = *(const bf16x8*)(shA + (rt * 16 + l) * KPAD + s * 32 + q * 8);
#pragma unroll
      for (int ct = 0; ct < 4; ct++)
        acc[rt][ct] = __builtin_amdgcn_mfma_f32_16x16x32_bf16(af, bfr[ct], acc[rt][ct], 0, 0, 0);
    }
  }
}

// matmul + 16-col score columns (wave 0 only), af per-rt
template<int KS>
__device__ __forceinline__ void mfma_mm_sc(const __bf16* __restrict__ Bp,
                                           const __bf16* __restrict__ SAp,
                                           f32x4 acc[4][4], f32x4 acc_sc[4],
                                           const __bf16* __restrict__ shA,
                                           int l, int q, int colbase8)
{
#pragma unroll
  for (int s = 0; s < KS; s++) {
    bf16x8 bfr[4], bsc;
#pragma unroll
    for (int ct = 0; ct < 4; ct++)
      bfr[ct] = *(const bf16x8*)(Bp + (s * 4 + q) * 2048 + colbase8 + ct * 128);
    bsc = *(const bf16x8*)(SAp + (s * 4 + q) * 128 + l * 8);
#pragma unroll
    for (int rt = 0; rt < 4; rt++) {
      bf16x8 af = *(const bf16x8*)(shA + (rt * 16 + l) * KPAD + s * 32 + q * 8);
#pragma unroll
      for (int ct = 0; ct < 4; ct++)
        acc[rt][ct] = __builtin_amdgcn_mfma_f32_16x16x32_bf16(af, bfr[ct], acc[rt][ct], 0, 0, 0);
      acc_sc[rt] = __builtin_amdgcn_mfma_f32_16x16x32_bf16(af, bsc, acc_sc[rt], 0, 0, 0);
    }
  }
}

__global__ __launch_bounds__(256, 2)
void gat_poly_kernel(const float* __restrict__ x,
                     const float* __restrict__ b0, const float* __restrict__ b1,
                     const float* __restrict__ b2, const float* __restrict__ b3,
                     const float* __restrict__ h1b, const float* __restrict__ h2b,
                     const __bf16* __restrict__ WP,
                     const float* __restrict__ h2wt,
                     const float* __restrict__ d_temb,
                     float* __restrict__ out)
{
  __shared__ __bf16 bufA[VN * KPAD];
  __shared__ __bf16 bufB[VN * KPAD];
  __shared__ float  sh_temb[128];
  __shared__ float  sh_ssp[VN * 4];      // s_src [n][head]
  __shared__ float  sh_stp[VN * 4];      // s_tgt [n][head]
  __shared__ float  sh_al[VN][4][3];     // alphas [n][head][edge]

  const int b    = blockIdx.x;
  const int tid  = threadIdx.x;
  const int w    = tid >> 6;
  const int lane = tid & 63;
  const int l    = lane & 15;
  const int q    = lane >> 4;
  const int cb   = w * 64;
  const int colbase8 = (cb + l) * 8;

  // flat-epilogue indexing: f-pair + node half
  const int fp = (tid & 127) * 2;
  const int nb = (tid >> 7) * 32;
  const int fhd = fp >> 6;

  __bf16* hb = bufA;   // current activations (MFMA A source)
  __bf16* ag = bufB;   // skip+bias staging / proj buffer

  if (tid < 128) sh_temb[tid] = d_temb[b * 128 + tid];
  __syncthreads();

  // ------------- h0 = [coords(2), pos(4), temb(128)], zero pad to 160 --------
  for (int idx = tid; idx < VN * 160; idx += 256) {
    int n = idx / 160, k = idx - n * 160;
    float v = 0.0f;
    if (k < 2) {
      v = x[b * 128 + 2 * n + k];
    } else if (k < 6) {
      float ph  = (float)n * 0.09817477042468103f;  // 2*pi/64
      float arg = (k < 4) ? ph : 2.0f * ph;
      v = ((k & 1) == 0) ? sinf(arg) : cosf(arg);
    } else if (k < 134) {
      v = sh_temb[k - 6];
    }
    hb[n * KPAD + k] = (__bf16)v;
  }
  __syncthreads();

  const int WOFFS[3]  = {OFF_W0, OFF_W1, OFF_W2};
  const int SOFFS[3]  = {OFF_SK0, OFF_SK1, OFF_SK2};
  const int SAOFFS[3] = {OFF_SA0, OFF_SA1, OFF_SA2};
  const float* Bs[3]  = {b0, b1, b2};

  // ---------------- GAT layers 0..2 (NH=4, FOUT=64, concat + elu) ------------
  for (int li = 0; li < 3; li++) {
    // ---- pass A: skip projection + bias -> ag (bf16, lane-owned) ----
    {
      f32x4 accS[4][4];
#pragma unroll
      for (int rt = 0; rt < 4; rt++)
#pragma unroll
        for (int ct = 0; ct < 4; ct++) accS[rt][ct] = (f32x4)0.0f;
      if (li == 0) mfma_mm<5>(WP + OFF_SK0,   accS, hb, l, q, colbase8);
      else         mfma_mm<8>(WP + SOFFS[li], accS, hb, l, q, colbase8);
      float b4[4];
#pragma unroll
      for (int ct = 0; ct < 4; ct++) b4[ct] = Bs[li][cb + ct * 16 + l];
#pragma unroll
      for (int rt = 0; rt < 4; rt++)
#pragma unroll
        for (int reg = 0; reg < 4; reg++) {
          int n = rt * 16 + q * 4 + reg;
#pragma unroll
          for (int ct = 0; ct < 4; ct++)
            ag[n * KPAD + cb + ct * 16 + l] = (__bf16)(accS[rt][ct][reg] + b4[ct]);
        }
    }

    // ---- pass B: main projection; score columns on wave 0 only ----
    f32x4 acc[4][4];
#pragma unroll
    for (int rt = 0; rt < 4; rt++)
#pragma unroll
      for (int ct = 0; ct < 4; ct++) acc[rt][ct] = (f32x4)0.0f;

    if (w == 0) {
      f32x4 acc_sc[4];
#pragma unroll
      for (int rt = 0; rt < 4; rt++) acc_sc[rt] = (f32x4)0.0f;
      if (li == 0) mfma_mm_sc<5>(WP + OFF_W0,    WP + OFF_SA0,    acc, acc_sc, hb, l, q, colbase8);
      else         mfma_mm_sc<8>(WP + WOFFS[li], WP + SAOFFS[li], acc, acc_sc, hb, l, q, colbase8);
      if (l < 8) {   // col l<4 = s_src head l, 4..7 = s_tgt head l-4
#pragma unroll
        for (int rt = 0; rt < 4; rt++)
#pragma unroll
          for (int reg = 0; reg < 4; reg++) {
            int n = rt * 16 + q * 4 + reg;
            float v = acc_sc[rt][reg];
            if (l < 4) sh_ssp[n * 4 + l] = v;
            else       sh_stp[n * 4 + (l - 4)] = v;
          }
      }
    } else {
      if (li == 0) mfma_mm<5>(WP + OFF_W0,    acc, hb, l, q, colbase8);
      else         mfma_mm<8>(WP + WOFFS[li], acc, hb, l, q, colbase8);
    }
    __syncthreads();   // all hb reads done (A+B); scores visible

    // proj dump: acc -> hb (bf16, lane-owned; h is dead now)
#pragma unroll
    for (int rt = 0; rt < 4; rt++)
#pragma unroll
      for (int reg = 0; reg < 4; reg++) {
        int n = rt * 16 + q * 4 + reg;
#pragma unroll
        for (int ct = 0; ct < 4; ct++)
          hb[n * KPAD + cb + ct * 16 + l] = (__bf16)acc[rt][ct][reg];
      }

    { // softmax over {prv,nxt,self}: thread per (node, head) — proven r2 form
      int n = tid >> 2, hd = tid & 3;
      int prv = (n + 63) & 63, nxt = (n + 1) & 63;
      float stg = sh_stp[n * 4 + hd];
      float e0 = sh_ssp[prv * 4 + hd] + stg; e0 = (e0 < 0.0f) ? 0.2f * e0 : e0;
      float e1 = sh_ssp[nxt * 4 + hd] + stg; e1 = (e1 < 0.0f) ? 0.2f * e1 : e1;
      float e2 = sh_ssp[n * 4 + hd]   + stg; e2 = (e2 < 0.0f) ? 0.2f * e2 : e2;
      float mx = fmaxf(e0, fmaxf(e1, e2));
      float x0 = expf(e0 - mx), x1 = expf(e1 - mx), x2 = expf(e2 - mx);
      float inv = 1.0f / (x0 + x1 + x2 + 1e-16f);
      sh_al[n][hd][0] = x0 * inv;
      sh_al[n][hd][1] = x1 * inv;
      sh_al[n][hd][2] = x2 * inv;
    }
    __syncthreads();   // proj + alphas visible

    // ---- flat epilogue: o = elu(a0*proj[prv]+a1*proj[nxt]+a2*proj[n] + ag)
    //      thread owns f-pair fp, nodes nb..nb+31; lane-private RMW on ag ----
    {
      float pm0, pm1, pc0, pc1;
      { bf16x2 v = *(const bf16x2*)(hb + ((nb + 63) & 63) * KPAD + fp); pm0 = v[0]; pm1 = v[1]; }
      { bf16x2 v = *(const bf16x2*)(hb + nb * KPAD + fp);               pc0 = v[0]; pc1 = v[1]; }
#pragma unroll 8
      for (int i = 0; i < 32; i++) {
        int n = nb + i;
        bf16x2 pnv = *(const bf16x2*)(hb + ((n + 1) & 63) * KPAD + fp);
        bf16x2 agv = *(const bf16x2*)(ag + n * KPAD + fp);
        float a0 = sh_al[n][fhd][0], a1 = sh_al[n][fhd][1], a2 = sh_al[n][fhd][2];
        float o0 = a0 * pm0 + a1 * (float)pnv[0] + a2 * pc0 + (float)agv[0];
        float o1 = a0 * pm1 + a1 * (float)pnv[1] + a2 * pc1 + (float)agv[1];
        o0 = (o0 > 0.0f) ? o0 : (expf(o0) - 1.0f);
        o1 = (o1 > 0.0f) ? o1 : (expf(o1) - 1.0f);
        bf16x2 ov; ov[0] = (__bf16)o0; ov[1] = (__bf16)o1;
        *(bf16x2*)(ag + n * KPAD + fp) = ov;
        pm0 = pc0; pm1 = pc1; pc0 = (float)pnv[0]; pc1 = (float)pnv[1];
      }
    }
    __syncthreads();   // new h (in ag) complete

    __bf16* tmp = hb; hb = ag; ag = tmp;   // ping-pong
  }

  // ---------------- GAT layer 3 (NH=1, FOUT=256, identity skip, no act) ------
  {
    f32x4 acc[4][4];
#pragma unroll
    for (int rt = 0; rt < 4; rt++)
#pragma unroll
      for (int ct = 0; ct < 4; ct++) acc[rt][ct] = (f32x4)0.0f;

    if (w == 0) {
      f32x4 acc_sc[4];
#pragma unroll
      for (int rt = 0; rt < 4; rt++) acc_sc[rt] = (f32x4)0.0f;
      mfma_mm_sc<8>(WP + OFF_W3, WP + OFF_SA3, acc, acc_sc, hb, l, q, colbase8);
      if (l < 2) {   // col 0 = s_src, col 1 = s_tgt
#pragma unroll
        for (int rt = 0; rt < 4; rt++)
#pragma unroll
          for (int reg = 0; reg < 4; reg++) {
            int n = rt * 16 + q * 4 + reg;
            float v = acc_sc[rt][reg];
            if (l == 0) sh_ssp[n * 4] = v;
            else        sh_stp[n * 4] = v;
          }
      }
    } else {
      mfma_mm<8>(WP + OFF_W3, acc, hb, l, q, colbase8);
    }
    __syncthreads();

    // proj dump: acc -> ag (hb holds h, needed for residual)
#pragma unroll
    for (int rt = 0; rt < 4; rt++)
#pragma unroll
      for (int reg = 0; reg < 4; reg++) {
        int n = rt * 16 + q * 4 + reg;
#pragma unroll
        for (int ct = 0; ct < 4; ct++)
          ag[n * KPAD + cb + ct * 16 + l] = (__bf16)acc[rt][ct][reg];
      }

    if (tid < 64) {  // softmax, single head
      int n = tid;
      float ssn = sh_ssp[n * 4];
      float stn = sh_stp[n * 4];
      float ssp = __shfl(ssn, (n + 63) & 63, 64);
      float ssx = __shfl(ssn, (n + 1) & 63, 64);
      float e0 = ssp + stn; e0 = (e0 < 0.0f) ? 0.2f * e0 : e0;
      float e1 = ssx + stn; e1 = (e1 < 0.0f) ? 0.2f * e1 : e1;
      float e2 = ssn + stn; e2 = (e2 < 0.0f) ? 0.2f * e2 : e2;
      float mx = fmaxf(e0, fmaxf(e1, e2));
      float x0 = expf(e0 - mx), x1 = expf(e1 - mx), x2 = expf(e2 - mx);
      float inv = 1.0f / (x0 + x1 + x2 + 1e-16f);
      sh_al[n][0][0] = x0 * inv;
      sh_al[n][0][1] = x1 * inv;
      sh_al[n][0][2] = x2 * inv;
    }
    __syncthreads();

    { // flat epilogue: o = gather(ag) + hb(residual) + b3 -> hb (lane-private RMW)
      float b30 = b3[fp], b31 = b3[fp + 1];
      float pm0, pm1, pc0, pc1;
      { bf16x2 v = *(const bf16x2*)(ag + ((nb + 63) & 63) * KPAD + fp); pm0 = v[0]; pm1 = v[1]; }
      { bf16x2 v = *(const bf16x2*)(ag + nb * KPAD + fp);               pc0 = v[0]; pc1 = v[1]; }
#pragma unroll 8
      for (int i = 0; i < 32; i++) {
        int n = nb + i;
        bf16x2 pnv = *(const bf16x2*)(ag + ((n + 1) & 63) * KPAD + fp);
        bf16x2 hrv = *(const bf16x2*)(hb + n * KPAD + fp);
        float a0 = sh_al[n][0][0], a1 = sh_al[n][0][1], a2 = sh_al[n][0][2];
        float o0 = a0 * pm0 + a1 * (float)pnv[0] + a2 * pc0 + (float)hrv[0] + b30;
        float o1 = a0 * pm1 + a1 * (float)pnv[1] + a2 * pc1 + (float)hrv[1] + b31;
        bf16x2 ov; ov[0] = (__bf16)o0; ov[1] = (__bf16)o1;
        *(bf16x2*)(hb + n * KPAD + fp) = ov;
        pm0 = pc0; pm1 = pc1; pc0 = (float)pnv[0]; pc1 = (float)pnv[1];
      }
    }
    __syncthreads();
  }

  // ---------------- head MLP: silu(h@h1W+h1b), then h@h2W+h2b ----------------
  {
    f32x4 acc[4][4];
#pragma unroll
    for (int rt = 0; rt < 4; rt++)
#pragma unroll
      for (int ct = 0; ct < 4; ct++) acc[rt][ct] = (f32x4)0.0f;
    mfma_mm<8>(WP + OFF_H1W, acc, hb, l, q, colbase8);
    __syncthreads();

    float b4[4];
#pragma unroll
    for (int ct = 0; ct < 4; ct++) b4[ct] = h1b[cb + ct * 16 + l];
#pragma unroll
    for (int rt = 0; rt < 4; rt++)
#pragma unroll
      for (int reg = 0; reg < 4; reg++) {
        int n = rt * 16 + q * 4 + reg;
#pragma unroll
        for (int ct = 0; ct < 4; ct++) {
          float o = acc[rt][ct][reg] + b4[ct];
          o = o / (1.0f + expf(-o));
          hb[n * KPAD + cb + ct * 16 + l] = (__bf16)o;
        }
      }
    __syncthreads();

    { // final 256 -> 2, all 256 threads: split-K by 2 + pair combine
      int n = tid >> 2, c = (tid >> 1) & 1, half = tid & 1;
      const float* wrow = h2wt + c * 256 + half * 128;
      const __bf16* hrow = hb + n * KPAD + half * 128;
      float o = half ? 0.0f : h2b[c];
#pragma unroll 4
      for (int k8 = 0; k8 < 16; k8++) {
        bf16x8 hv = *(const bf16x8*)(hrow + k8 * 8);
        f32x4 w0 = *(const f32x4*)(wrow + k8 * 8);
        f32x4 w1 = *(const f32x4*)(wrow + k8 * 8 + 4);
#pragma unroll
        for (int j = 0; j < 4; j++) o = fmaf((float)hv[j], w0[j], o);
#pragma unroll
        for (int j = 0; j < 4; j++) o = fmaf((float)hv[4 + j], w1[j], o);
      }
      o += __shfl_xor(o, 1, 64);
      if (!half) out[b * 128 + 2 * n + c] = o;
    }
  }
}

extern "C" void kernel_launch(void* const* d_in, const int* in_sizes, int n_in,
                              void* d_out, int out_size, void* d_ws, size_t ws_size,
                              hipStream_t stream)
{
  auto fp = [&](int i) { return (const float*)d_in[i]; };
  __bf16* wp   = (__bf16*)d_ws;
  float* h2wt  = (float*)(wp + OFF_END);        // 512 fp32 (16B aligned)
  float* dtemb = h2wt + 512;                    // 2048*128 fp32

  setup_all<<<2940, 256, 0, stream>>>(fp(4), fp(20), fp(8), fp(21),
                                      fp(12), fp(22), fp(16), fp(23),
                                      fp(25),
                                      fp(5),  fp(6),  fp(9),  fp(10),
                                      fp(13), fp(14), fp(17), fp(18),
                                      (const int*)d_in[1], fp(2), fp(3),
                                      h2wt, dtemb, wp);

  gat_poly_kernel<<<2048, 256, 0, stream>>>(
      fp(0),
      fp(7), fp(11), fp(15), fp(19),   // b0..b3
      fp(24), fp(26),                  // h1b h2b
      wp, h2wt, dtemb,
      (float*)d_out);
}

// Round 16
// 377.561 us; speedup vs baseline: 1.4850x; 1.1341x over previous
//
#include <hip/hip_runtime.h>
#include <hip/hip_bf16.h>

#define VN    64
#define KPAD  264   // bf16 row stride: rows 16B-aligned (528B)

typedef __bf16 bf16x8 __attribute__((ext_vector_type(8)));
typedef __bf16 bf16x2 __attribute__((ext_vector_type(2)));
typedef float  f32x4  __attribute__((ext_vector_type(4)));

// fast transcendentals: v_exp_f32 / v_rcp_f32 (1-2 ulp fp32; output rounds to bf16)
__device__ __forceinline__ float fexp(float x) { return __expf(x); }
__device__ __forceinline__ float frcp(float x) { return __builtin_amdgcn_rcpf(x); }

// packed-weight bf16 element offsets in d_ws
#define OFF_W0   0
#define OFF_SK0  40960
#define OFF_W1   81920
#define OFF_SK1  147456
#define OFF_W2   212992
#define OFF_SK2  278528
#define OFF_W3   344064
#define OFF_H1W  409600
#define OFF_SA0  475136    // score cols layer0: 160 x 16
#define OFF_SA1  477696    // 256 x 16
#define OFF_SA2  481792
#define OFF_SA3  485888
#define OFF_END  489984    // bf16 elems; byte 979968 (16B aligned)

// ---- one fused setup kernel (r11 form) ----
__global__ void setup_all(const float* __restrict__ W0s, const float* __restrict__ sk0s,
                          const float* __restrict__ W1s, const float* __restrict__ sk1s,
                          const float* __restrict__ W2s, const float* __restrict__ sk2s,
                          const float* __restrict__ W3s, const float* __restrict__ h1Ws,
                          const float* __restrict__ h2W,
                          const float* __restrict__ as0, const float* __restrict__ at0,
                          const float* __restrict__ as1, const float* __restrict__ at1,
                          const float* __restrict__ as2, const float* __restrict__ at2,
                          const float* __restrict__ as3, const float* __restrict__ at3,
                          const int* __restrict__ t, const float* __restrict__ tW,
                          const float* __restrict__ tb,
                          float* __restrict__ h2wt, float* __restrict__ d_temb,
                          __bf16* __restrict__ wp)
{
  int blk = blockIdx.x, tid = threadIdx.x;
  if (blk < 1856) {
    const float* src; int fin, dstoff, rel;
    if (blk < 320) {
      if (blk < 160) { src = W0s;  dstoff = OFF_W0;  rel = blk; }
      else           { src = sk0s; dstoff = OFF_SK0; rel = blk - 160; }
      fin = 134;
    } else {
      int r = (blk - 320) >> 8;
      rel = (blk - 320) & 255;
      const float* srcs[6] = {W1s, sk1s, W2s, sk2s, W3s, h1Ws};
      const int    offs[6] = {OFF_W1, OFF_SK1, OFF_W2, OFF_SK2, OFF_W3, OFF_H1W};
      src = srcs[r]; dstoff = offs[r]; fin = 256;
    }
    int idx = rel * 256 + tid;
    int rr = idx & 7, n = (idx >> 3) & 255, c = idx >> 11;
    int k = c * 8 + rr;
    float v = (k < fin) ? src[k * 256 + n] : 0.0f;
    wp[dstoff + idx] = (__bf16)v;
  } else if (blk < 1858) {
    int idx = (blk - 1856) * 256 + tid;
    int c = idx >> 8, k = idx & 255;
    h2wt[idx] = h2W[k * 2 + c];
  } else if (blk < 1916) {
    int idx = (blk - 1858) * 256 + tid;   // 928 rows x 16 cols = 14848
    if (idx < 14848) {
      int gk = idx >> 4, c = idx & 15;
      int li, k, fin, dstoff;
      if (gk < 160)      { li = 0; k = gk;       fin = 134; dstoff = OFF_SA0; }
      else if (gk < 416) { li = 1; k = gk - 160; fin = 256; dstoff = OFF_SA1; }
      else if (gk < 672) { li = 2; k = gk - 416; fin = 256; dstoff = OFF_SA2; }
      else               { li = 3; k = gk - 672; fin = 256; dstoff = OFF_SA3; }
      float v = 0.0f;
      if (k < fin) {
        if (li < 3) {
          if (c < 8) {
            int hd = c & 3;
            const float* Wm = (li == 0) ? W0s : (li == 1) ? W1s : W2s;
            const float* a  = (c < 4) ? ((li == 0) ? as0 : (li == 1) ? as1 : as2)
                                      : ((li == 0) ? at0 : (li == 1) ? at1 : at2);
            for (int f = 0; f < 64; f++)
              v += Wm[k * 256 + hd * 64 + f] * a[hd * 64 + f];
          }
        } else {
          if (c < 2) {
            const float* a = (c == 0) ? as3 : at3;
            for (int f = 0; f < 256; f++)
              v += W3s[k * 256 + f] * a[f];
          }
        }
      }
      wp[dstoff + ((k >> 3) * 16 + c) * 8 + (k & 7)] = (__bf16)v;
    }
  } else {
    // temb: 2 polygons per block, 128 threads each
    __shared__ float se[2][128];
    int half = tid >> 7, tt = tid & 127;
    int b = (blk - 1916) * 2 + half;
    int fi = tt & 63;
    float fr = expf(-logf(10000.0f) * (float)fi / 63.0f);
    float te = (float)t[b] * fr;
    se[half][tt] = (tt < 64) ? sinf(te) : cosf(te);
    __syncthreads();
    float a = tb[tt];
    for (int k = 0; k < 128; k++)
      a = fmaf(se[half][k], tW[k * 128 + tt], a);
    d_temb[b * 128 + tt] = a * frcp(1.0f + fexp(-a));
  }
}

// single-B matmul: acc += A(64 x 32*KS from LDS) @ B(packed global)  [r11 form]
template<int KS>
__device__ __forceinline__ void mfma_mm(const __bf16* __restrict__ Bp,
                                        f32x4 acc[4][4],
                                        const __bf16* __restrict__ shA,
                                        int l, int q, int colbase8)
{
#pragma unroll
  for (int s = 0; s < KS; s++) {
    bf16x8 af[4], bfr[4];
#pragma unroll
    for (int rt = 0; rt < 4; rt++)
      af[rt] = *(const bf16x8*)(shA + (rt * 16 + l) * KPAD + s * 32 + q * 8);
#pragma unroll
    for (int ct = 0; ct < 4; ct++)
      bfr[ct] = *(const bf16x8*)(Bp + (s * 4 + q) * 2048 + colbase8 + ct * 128);
#pragma unroll
    for (int rt = 0; rt < 4; rt++)
#pragma unroll
      for (int ct = 0; ct < 4; ct++)
        acc[rt][ct] = __builtin_amdgcn_mfma_f32_16x16x32_bf16(af[rt], bfr[ct], acc[rt][ct], 0, 0, 0);
  }
}

// matmul + score columns: acc += A@B, acc_sc += A@SA (16-col packed)  [r11 form]
template<int KS>
__device__ __forceinline__ void mfma_mm_sc(const __bf16* __restrict__ Bp,
                                           const __bf16* __restrict__ SAp,
                                           f32x4 acc[4][4], f32x4 acc_sc[4],
                                           const __bf16* __restrict__ shA,
                                           int l, int q, int colbase8)
{
#pragma unroll
  for (int s = 0; s < KS; s++) {
    bf16x8 af[4], bfr[4], bsc;
#pragma unroll
    for (int rt = 0; rt < 4; rt++)
      af[rt] = *(const bf16x8*)(shA + (rt * 16 + l) * KPAD + s * 32 + q * 8);
#pragma unroll
    for (int ct = 0; ct < 4; ct++)
      bfr[ct] = *(const bf16x8*)(Bp + (s * 4 + q) * 2048 + colbase8 + ct * 128);
    bsc = *(const bf16x8*)(SAp + (s * 4 + q) * 128 + l * 8);
#pragma unroll
    for (int rt = 0; rt < 4; rt++) {
#pragma unroll
      for (int ct = 0; ct < 4; ct++)
        acc[rt][ct] = __builtin_amdgcn_mfma_f32_16x16x32_bf16(af[rt], bfr[ct], acc[rt][ct], 0, 0, 0);
      acc_sc[rt] = __builtin_amdgcn_mfma_f32_16x16x32_bf16(af[rt], bsc, acc_sc[rt], 0, 0, 0);
    }
  }
}

__global__ __launch_bounds__(256, 2)
void gat_poly_kernel(const float* __restrict__ x,
                     const float* __restrict__ b0, const float* __restrict__ b1,
                     const float* __restrict__ b2, const float* __restrict__ b3,
                     const float* __restrict__ h1b, const float* __restrict__ h2b,
                     const __bf16* __restrict__ WP,
                     const float* __restrict__ h2wt,
                     const float* __restrict__ d_temb,
                     float* __restrict__ out)
{
  __shared__ __bf16 bufA[VN * KPAD];
  __shared__ __bf16 bufB[VN * KPAD];
  __shared__ float  sh_temb[128];
  __shared__ float  sh_ssp[VN * 4];      // s_src [n][head]
  __shared__ float  sh_stp[VN * 4];      // s_tgt [n][head]
  __shared__ float  sh_al[VN][4][3];     // alphas [n][head][edge]

  const int b    = blockIdx.x;
  const int tid  = threadIdx.x;
  const int w    = tid >> 6;
  const int lane = tid & 63;
  const int l    = lane & 15;
  const int q    = lane >> 4;
  const int cb   = w * 64;
  const int colbase8 = (cb + l) * 8;

  // flat-epilogue indexing: f-pair + node half
  const int fp = (tid & 127) * 2;
  const int nb = (tid >> 7) * 32;
  const int fhd = fp >> 6;

  __bf16* hb = bufA;   // current activations (MFMA A source)
  __bf16* ag = bufB;   // skip+bias staging / proj buffer

  if (tid < 128) sh_temb[tid] = d_temb[b * 128 + tid];
  __syncthreads();

  // ------------- h0 = [coords(2), pos(4), temb(128)], zero pad to 160 --------
  for (int idx = tid; idx < VN * 160; idx += 256) {
    int n = idx / 160, k = idx - n * 160;
    float v = 0.0f;
    if (k < 2) {
      v = x[b * 128 + 2 * n + k];
    } else if (k < 6) {
      float ph  = (float)n * 0.09817477042468103f;  // 2*pi/64
      float arg = (k < 4) ? ph : 2.0f * ph;
      v = ((k & 1) == 0) ? sinf(arg) : cosf(arg);
    } else if (k < 134) {
      v = sh_temb[k - 6];
    }
    hb[n * KPAD + k] = (__bf16)v;
  }
  __syncthreads();

  const int WOFFS[3]  = {OFF_W0, OFF_W1, OFF_W2};
  const int SOFFS[3]  = {OFF_SK0, OFF_SK1, OFF_SK2};
  const int SAOFFS[3] = {OFF_SA0, OFF_SA1, OFF_SA2};
  const float* Bs[3]  = {b0, b1, b2};

  // ---------------- GAT layers 0..2 (NH=4, FOUT=64, concat + elu) ------------
  for (int li = 0; li < 3; li++) {
    // ---- pass A: skip projection + bias -> ag (bf16, lane-owned) ----
    {
      f32x4 accS[4][4];
#pragma unroll
      for (int rt = 0; rt < 4; rt++)
#pragma unroll
        for (int ct = 0; ct < 4; ct++) accS[rt][ct] = (f32x4)0.0f;
      if (li == 0) mfma_mm<5>(WP + OFF_SK0,   accS, hb, l, q, colbase8);
      else         mfma_mm<8>(WP + SOFFS[li], accS, hb, l, q, colbase8);
      float b4[4];
#pragma unroll
      for (int ct = 0; ct < 4; ct++) b4[ct] = Bs[li][cb + ct * 16 + l];
#pragma unroll
      for (int rt = 0; rt < 4; rt++)
#pragma unroll
        for (int reg = 0; reg < 4; reg++) {
          int n = rt * 16 + q * 4 + reg;
#pragma unroll
          for (int ct = 0; ct < 4; ct++)
            ag[n * KPAD + cb + ct * 16 + l] = (__bf16)(accS[rt][ct][reg] + b4[ct]);
        }
    }

    // ---- pass B: main projection + score columns (all waves, uniform) ----
    f32x4 acc[4][4], acc_sc[4];
#pragma unroll
    for (int rt = 0; rt < 4; rt++) {
#pragma unroll
      for (int ct = 0; ct < 4; ct++) acc[rt][ct] = (f32x4)0.0f;
      acc_sc[rt] = (f32x4)0.0f;
    }
    if (li == 0) mfma_mm_sc<5>(WP + OFF_W0,    WP + OFF_SA0,    acc, acc_sc, hb, l, q, colbase8);
    else         mfma_mm_sc<8>(WP + WOFFS[li], WP + SAOFFS[li], acc, acc_sc, hb, l, q, colbase8);

    // scores -> LDS: col l<4 = s_src head l, col 4..7 = s_tgt (r10-proven)
    if (l < 8) {
#pragma unroll
      for (int rt = 0; rt < 4; rt++)
#pragma unroll
        for (int reg = 0; reg < 4; reg++) {
          int n = rt * 16 + q * 4 + reg;
          float v = acc_sc[rt][reg];
          if (l < 4) sh_ssp[n * 4 + l] = v;
          else       sh_stp[n * 4 + (l - 4)] = v;
        }
    }
    __syncthreads();   // all hb reads done (A+B); scores visible

    // proj dump: acc -> hb (bf16, lane-owned; h is dead now)
#pragma unroll
    for (int rt = 0; rt < 4; rt++)
#pragma unroll
      for (int reg = 0; reg < 4; reg++) {
        int n = rt * 16 + q * 4 + reg;
#pragma unroll
        for (int ct = 0; ct < 4; ct++)
          hb[n * KPAD + cb + ct * 16 + l] = (__bf16)acc[rt][ct][reg];
      }

    { // softmax over {prv,nxt,self}: thread per (node, head)
      int n = tid >> 2, hd = tid & 3;
      int prv = (n + 63) & 63, nxt = (n + 1) & 63;
      float stg = sh_stp[n * 4 + hd];
      float e0 = sh_ssp[prv * 4 + hd] + stg; e0 = (e0 < 0.0f) ? 0.2f * e0 : e0;
      float e1 = sh_ssp[nxt * 4 + hd] + stg; e1 = (e1 < 0.0f) ? 0.2f * e1 : e1;
      float e2 = sh_ssp[n * 4 + hd]   + stg; e2 = (e2 < 0.0f) ? 0.2f * e2 : e2;
      float mx = fmaxf(e0, fmaxf(e1, e2));
      float x0 = fexp(e0 - mx), x1 = fexp(e1 - mx), x2 = fexp(e2 - mx);
      float inv = frcp(x0 + x1 + x2 + 1e-16f);
      sh_al[n][hd][0] = x0 * inv;
      sh_al[n][hd][1] = x1 * inv;
      sh_al[n][hd][2] = x2 * inv;
    }
    __syncthreads();   // proj + alphas visible

    // ---- flat epilogue: o = elu(a0*proj[prv]+a1*proj[nxt]+a2*proj[n] + ag)
    //      thread owns f-pair fp, nodes nb..nb+31; lane-private RMW on ag ----
    {
      float pm0, pm1, pc0, pc1;
      { bf16x2 v = *(const bf16x2*)(hb + ((nb + 63) & 63) * KPAD + fp); pm0 = v[0]; pm1 = v[1]; }
      { bf16x2 v = *(const bf16x2*)(hb + nb * KPAD + fp);               pc0 = v[0]; pc1 = v[1]; }
#pragma unroll 8
      for (int i = 0; i < 32; i++) {
        int n = nb + i;
        bf16x2 pnv = *(const bf16x2*)(hb + ((n + 1) & 63) * KPAD + fp);
        bf16x2 agv = *(const bf16x2*)(ag + n * KPAD + fp);
        float a0 = sh_al[n][fhd][0], a1 = sh_al[n][fhd][1], a2 = sh_al[n][fhd][2];
        float o0 = a0 * pm0 + a1 * (float)pnv[0] + a2 * pc0 + (float)agv[0];
        float o1 = a0 * pm1 + a1 * (float)pnv[1] + a2 * pc1 + (float)agv[1];
        o0 = (o0 > 0.0f) ? o0 : (fexp(o0) - 1.0f);
        o1 = (o1 > 0.0f) ? o1 : (fexp(o1) - 1.0f);
        bf16x2 ov; ov[0] = (__bf16)o0; ov[1] = (__bf16)o1;
        *(bf16x2*)(ag + n * KPAD + fp) = ov;
        pm0 = pc0; pm1 = pc1; pc0 = (float)pnv[0]; pc1 = (float)pnv[1];
      }
    }
    __syncthreads();   // new h (in ag) complete

    __bf16* tmp = hb; hb = ag; ag = tmp;   // ping-pong
  }

  // ---------------- GAT layer 3 (NH=1, FOUT=256, identity skip, no act) ------
  {
    f32x4 acc[4][4], acc_sc[4];
#pragma unroll
    for (int rt = 0; rt < 4; rt++) {
#pragma unroll
      for (int ct = 0; ct < 4; ct++) acc[rt][ct] = (f32x4)0.0f;
      acc_sc[rt] = (f32x4)0.0f;
    }
    mfma_mm_sc<8>(WP + OFF_W3, WP + OFF_SA3, acc, acc_sc, hb, l, q, colbase8);

    if (l < 2) {   // col 0 = s_src, col 1 = s_tgt
#pragma unroll
      for (int rt = 0; rt < 4; rt++)
#pragma unroll
        for (int reg = 0; reg < 4; reg++) {
          int n = rt * 16 + q * 4 + reg;
          float v = acc_sc[rt][reg];
          if (l == 0) sh_ssp[n * 4] = v;
          else        sh_stp[n * 4] = v;
        }
    }
    __syncthreads();

    // proj dump: acc -> ag (hb holds h, needed for residual)
#pragma unroll
    for (int rt = 0; rt < 4; rt++)
#pragma unroll
      for (int reg = 0; reg < 4; reg++) {
        int n = rt * 16 + q * 4 + reg;
#pragma unroll
        for (int ct = 0; ct < 4; ct++)
          ag[n * KPAD + cb + ct * 16 + l] = (__bf16)acc[rt][ct][reg];
      }

    if (tid < 64) {  // softmax, single head
      int n = tid;
      float ssn = sh_ssp[n * 4];
      float stn = sh_stp[n * 4];
      float ssp = __shfl(ssn, (n + 63) & 63, 64);
      float ssx = __shfl(ssn, (n + 1) & 63, 64);
      float e0 = ssp + stn; e0 = (e0 < 0.0f) ? 0.2f * e0 : e0;
      float e1 = ssx + stn; e1 = (e1 < 0.0f) ? 0.2f * e1 : e1;
      float e2 = ssn + stn; e2 = (e2 < 0.0f) ? 0.2f * e2 : e2;
      float mx = fmaxf(e0, fmaxf(e1, e2));
      float x0 = fexp(e0 - mx), x1 = fexp(e1 - mx), x2 = fexp(e2 - mx);
      float inv = frcp(x0 + x1 + x2 + 1e-16f);
      sh_al[n][0][0] = x0 * inv;
      sh_al[n][0][1] = x1 * inv;
      sh_al[n][0][2] = x2 * inv;
    }
    __syncthreads();

    { // flat epilogue: o = gather(ag) + hb(residual) + b3 -> hb (lane-private RMW)
      float b30 = b3[fp], b31 = b3[fp + 1];
      float pm0, pm1, pc0, pc1;
      { bf16x2 v = *(const bf16x2*)(ag + ((nb + 63) & 63) * KPAD + fp); pm0 = v[0]; pm1 = v[1]; }
      { bf16x2 v = *(const bf16x2*)(ag + nb * KPAD + fp);               pc0 = v[0]; pc1 = v[1]; }
#pragma unroll 8
      for (int i = 0; i < 32; i++) {
        int n = nb + i;
        bf16x2 pnv = *(const bf16x2*)(ag + ((n + 1) & 63) * KPAD + fp);
        bf16x2 hrv = *(const bf16x2*)(hb + n * KPAD + fp);
        float a0 = sh_al[n][0][0], a1 = sh_al[n][0][1], a2 = sh_al[n][0][2];
        float o0 = a0 * pm0 + a1 * (float)pnv[0] + a2 * pc0 + (float)hrv[0] + b30;
        float o1 = a0 * pm1 + a1 * (float)pnv[1] + a2 * pc1 + (float)hrv[1] + b31;
        bf16x2 ov; ov[0] = (__bf16)o0; ov[1] = (__bf16)o1;
        *(bf16x2*)(hb + n * KPAD + fp) = ov;
        pm0 = pc0; pm1 = pc1; pc0 = (float)pnv[0]; pc1 = (float)pnv[1];
      }
    }
    __syncthreads();
  }

  // ---------------- head MLP: silu(h@h1W+h1b), then h@h2W+h2b ----------------
  {
    f32x4 acc[4][4];
#pragma unroll
    for (int rt = 0; rt < 4; rt++)
#pragma unroll
      for (int ct = 0; ct < 4; ct++) acc[rt][ct] = (f32x4)0.0f;
    mfma_mm<8>(WP + OFF_H1W, acc, hb, l, q, colbase8);
    __syncthreads();

    float b4[4];
#pragma unroll
    for (int ct = 0; ct < 4; ct++) b4[ct] = h1b[cb + ct * 16 + l];
#pragma unroll
    for (int rt = 0; rt < 4; rt++)
#pragma unroll
      for (int reg = 0; reg < 4; reg++) {
        int n = rt * 16 + q * 4 + reg;
#pragma unroll
        for (int ct = 0; ct < 4; ct++) {
          float o = acc[rt][ct][reg] + b4[ct];
          o = o * frcp(1.0f + fexp(-o));   // silu
          hb[n * KPAD + cb + ct * 16 + l] = (__bf16)o;
        }
      }
    __syncthreads();

    { // final 256 -> 2, all 256 threads: split-K by 2 + pair combine
      int n = tid >> 2, c = (tid >> 1) & 1, half = tid & 1;
      const float* wrow = h2wt + c * 256 + half * 128;
      const __bf16* hrow = hb + n * KPAD + half * 128;
      float o = half ? 0.0f : h2b[c];
#pragma unroll 4
      for (int k8 = 0; k8 < 16; k8++) {
        bf16x8 hv = *(const bf16x8*)(hrow + k8 * 8);
        f32x4 w0 = *(const f32x4*)(wrow + k8 * 8);
        f32x4 w1 = *(const f32x4*)(wrow + k8 * 8 + 4);
#pragma unroll
        for (int j = 0; j < 4; j++) o = fmaf((float)hv[j], w0[j], o);
#pragma unroll
        for (int j = 0; j < 4; j++) o = fmaf((float)hv[4 + j], w1[j], o);
      }
      o += __shfl_xor(o, 1, 64);
      if (!half) out[b * 128 + 2 * n + c] = o;
    }
  }
}

extern "C" void kernel_launch(void* const* d_in, const int* in_sizes, int n_in,
                              void* d_out, int out_size, void* d_ws, size_t ws_size,
                              hipStream_t stream)
{
  auto fp = [&](int i) { return (const float*)d_in[i]; };
  __bf16* wp   = (__bf16*)d_ws;
  float* h2wt  = (float*)(wp + OFF_END);        // 512 fp32 (16B aligned)
  float* dtemb = h2wt + 512;                    // 2048*128 fp32

  setup_all<<<2940, 256, 0, stream>>>(fp(4), fp(20), fp(8), fp(21),
                                      fp(12), fp(22), fp(16), fp(23),
                                      fp(25),
                                      fp(5),  fp(6),  fp(9),  fp(10),
                                      fp(13), fp(14), fp(17), fp(18),
                                      (const int*)d_in[1], fp(2), fp(3),
                                      h2wt, dtemb, wp);

  gat_poly_kernel<<<2048, 256, 0, stream>>>(
      fp(0),
      fp(7), fp(11), fp(15), fp(19),   // b0..b3
      fp(24), fp(26),                  // h1b h2b
      wp, h2wt, dtemb,
      (float*)d_out);
}

// Round 17
// 368.495 us; speedup vs baseline: 1.5215x; 1.0246x over previous
//
#include <hip/hip_runtime.h>
#include <hip/hip_bf16.h>

#define VN    64
#define KPAD  264   // bf16 row stride: rows 16B-aligned (528B)

typedef __bf16 bf16x8 __attribute__((ext_vector_type(8)));
typedef __bf16 bf16x4 __attribute__((ext_vector_type(4)));
typedef float  f32x4  __attribute__((ext_vector_type(4)));

// fast transcendentals: v_exp_f32 / v_rcp_f32 (1-2 ulp fp32; output rounds to bf16)
__device__ __forceinline__ float fexp(float x) { return __expf(x); }
__device__ __forceinline__ float frcp(float x) { return __builtin_amdgcn_rcpf(x); }

// packed-weight bf16 element offsets in d_ws
#define OFF_W0   0
#define OFF_SK0  40960
#define OFF_W1   81920
#define OFF_SK1  147456
#define OFF_W2   212992
#define OFF_SK2  278528
#define OFF_W3   344064
#define OFF_H1W  409600
#define OFF_SA0  475136    // score cols layer0: 160 x 16
#define OFF_SA1  477696    // 256 x 16
#define OFF_SA2  481792
#define OFF_SA3  485888
#define OFF_END  489984    // bf16 elems; byte 979968 (16B aligned)

// ---- fused setup kernel, pack stage coalesced via LDS transpose ----
// stripes of 16 rows: W0:10 sk0:10 then 6 x 16 = 116 pack blocks;
// 116..117 h2wt; 118..175 sa_pack; 176..1199 temb (2 polys/block)
__global__ void setup_all(const float* __restrict__ W0s, const float* __restrict__ sk0s,
                          const float* __restrict__ W1s, const float* __restrict__ sk1s,
                          const float* __restrict__ W2s, const float* __restrict__ sk2s,
                          const float* __restrict__ W3s, const float* __restrict__ h1Ws,
                          const float* __restrict__ h2W,
                          const float* __restrict__ as0, const float* __restrict__ at0,
                          const float* __restrict__ as1, const float* __restrict__ at1,
                          const float* __restrict__ as2, const float* __restrict__ at2,
                          const float* __restrict__ as3, const float* __restrict__ at3,
                          const int* __restrict__ t, const float* __restrict__ tW,
                          const float* __restrict__ tb,
                          float* __restrict__ h2wt, float* __restrict__ d_temb,
                          __bf16* __restrict__ wp)
{
  int blk = blockIdx.x, tid = threadIdx.x;
  if (blk < 116) {
    __shared__ float shw[16][257];
    const float* src; int fin, dstoff, s;
    if (blk < 20) {
      if (blk < 10) { src = W0s;  dstoff = OFF_W0;  s = blk; }
      else          { src = sk0s; dstoff = OFF_SK0; s = blk - 10; }
      fin = 134;
    } else {
      int r = (blk - 20) >> 4;                      // 0..5
      s = (blk - 20) & 15;
      const float* srcs[6] = {W1s, sk1s, W2s, sk2s, W3s, h1Ws};
      const int    offs[6] = {OFF_W1, OFF_SK1, OFF_W2, OFF_SK2, OFF_W3, OFF_H1W};
      src = srcs[r]; dstoff = offs[r]; fin = 256;
    }
    // coalesced read: 16 rows x 256 cols
#pragma unroll
    for (int it = 0; it < 16; it++) {
      int elem = it * 256 + tid;
      int r = elem >> 8, n = elem & 255;
      int k = s * 16 + r;
      shw[r][n] = (k < fin) ? src[k * 256 + n] : 0.0f;
    }
    __syncthreads();
    // coalesced packed write: lin = c_local*2048 + n*8 + k7
#pragma unroll
    for (int it = 0; it < 16; it++) {
      int lin = it * 256 + tid;
      int k7 = lin & 7, n = (lin >> 3) & 255, cl = lin >> 11;
      wp[dstoff + s * 4096 + lin] = (__bf16)shw[cl * 8 + k7][n];
    }
  } else if (blk < 118) {
    int idx = (blk - 116) * 256 + tid;
    int c = idx >> 8, k = idx & 255;
    h2wt[idx] = h2W[k * 2 + c];
  } else if (blk < 176) {
    int idx = (blk - 118) * 256 + tid;   // 928 rows x 16 cols = 14848
    if (idx < 14848) {
      int gk = idx >> 4, c = idx & 15;
      int li, k, fin, dstoff;
      if (gk < 160)      { li = 0; k = gk;       fin = 134; dstoff = OFF_SA0; }
      else if (gk < 416) { li = 1; k = gk - 160; fin = 256; dstoff = OFF_SA1; }
      else if (gk < 672) { li = 2; k = gk - 416; fin = 256; dstoff = OFF_SA2; }
      else               { li = 3; k = gk - 672; fin = 256; dstoff = OFF_SA3; }
      float v = 0.0f;
      if (k < fin) {
        if (li < 3) {
          if (c < 8) {
            int hd = c & 3;
            const float* Wm = (li == 0) ? W0s : (li == 1) ? W1s : W2s;
            const float* a  = (c < 4) ? ((li == 0) ? as0 : (li == 1) ? as1 : as2)
                                      : ((li == 0) ? at0 : (li == 1) ? at1 : at2);
            for (int f = 0; f < 64; f++)
              v += Wm[k * 256 + hd * 64 + f] * a[hd * 64 + f];
          }
        } else {
          if (c < 2) {
            const float* a = (c == 0) ? as3 : at3;
            for (int f = 0; f < 256; f++)
              v += W3s[k * 256 + f] * a[f];
          }
        }
      }
      wp[dstoff + ((k >> 3) * 16 + c) * 8 + (k & 7)] = (__bf16)v;
    }
  } else {
    // temb: 2 polygons per block, 128 threads each
    __shared__ float se[2][128];
    int half = tid >> 7, tt = tid & 127;
    int b = (blk - 176) * 2 + half;
    int fi = tt & 63;
    float fr = expf(-logf(10000.0f) * (float)fi / 63.0f);
    float te = (float)t[b] * fr;
    se[half][tt] = (tt < 64) ? sinf(te) : cosf(te);
    __syncthreads();
    float a = tb[tt];
    for (int k = 0; k < 128; k++)
      a = fmaf(se[half][k], tW[k * 128 + tt], a);
    d_temb[b * 128 + tt] = a * frcp(1.0f + fexp(-a));
  }
}

// single-B matmul: acc += A(64 x 32*KS from LDS) @ B(packed global)  [r11 form]
template<int KS>
__device__ __forceinline__ void mfma_mm(const __bf16* __restrict__ Bp,
                                        f32x4 acc[4][4],
                                        const __bf16* __restrict__ shA,
                                        int l, int q, int colbase8)
{
#pragma unroll
  for (int s = 0; s < KS; s++) {
    bf16x8 af[4], bfr[4];
#pragma unroll
    for (int rt = 0; rt < 4; rt++)
      af[rt] = *(const bf16x8*)(shA + (rt * 16 + l) * KPAD + s * 32 + q * 8);
#pragma unroll
    for (int ct = 0; ct < 4; ct++)
      bfr[ct] = *(const bf16x8*)(Bp + (s * 4 + q) * 2048 + colbase8 + ct * 128);
#pragma unroll
    for (int rt = 0; rt < 4; rt++)
#pragma unroll
      for (int ct = 0; ct < 4; ct++)
        acc[rt][ct] = __builtin_amdgcn_mfma_f32_16x16x32_bf16(af[rt], bfr[ct], acc[rt][ct], 0, 0, 0);
  }
}

// matmul + score columns: acc += A@B, acc_sc += A@SA (16-col packed)  [r11 form]
template<int KS>
__device__ __forceinline__ void mfma_mm_sc(const __bf16* __restrict__ Bp,
                                           const __bf16* __restrict__ SAp,
                                           f32x4 acc[4][4], f32x4 acc_sc[4],
                                           const __bf16* __restrict__ shA,
                                           int l, int q, int colbase8)
{
#pragma unroll
  for (int s = 0; s < KS; s++) {
    bf16x8 af[4], bfr[4], bsc;
#pragma unroll
    for (int rt = 0; rt < 4; rt++)
      af[rt] = *(const bf16x8*)(shA + (rt * 16 + l) * KPAD + s * 32 + q * 8);
#pragma unroll
    for (int ct = 0; ct < 4; ct++)
      bfr[ct] = *(const bf16x8*)(Bp + (s * 4 + q) * 2048 + colbase8 + ct * 128);
    bsc = *(const bf16x8*)(SAp + (s * 4 + q) * 128 + l * 8);
#pragma unroll
    for (int rt = 0; rt < 4; rt++) {
#pragma unroll
      for (int ct = 0; ct < 4; ct++)
        acc[rt][ct] = __builtin_amdgcn_mfma_f32_16x16x32_bf16(af[rt], bfr[ct], acc[rt][ct], 0, 0, 0);
      acc_sc[rt] = __builtin_amdgcn_mfma_f32_16x16x32_bf16(af[rt], bsc, acc_sc[rt], 0, 0, 0);
    }
  }
}

__global__ __launch_bounds__(256, 2)
void gat_poly_kernel(const float* __restrict__ x,
                     const float* __restrict__ b0, const float* __restrict__ b1,
                     const float* __restrict__ b2, const float* __restrict__ b3,
                     const float* __restrict__ h1b, const float* __restrict__ h2b,
                     const __bf16* __restrict__ WP,
                     const float* __restrict__ h2wt,
                     const float* __restrict__ d_temb,
                     float* __restrict__ out)
{
  __shared__ __bf16 bufA[VN * KPAD];
  __shared__ __bf16 bufB[VN * KPAD];
  __shared__ float  sh_temb[128];
  __shared__ float  sh_ssp[VN * 4];      // s_src [n][head]
  __shared__ float  sh_stp[VN * 4];      // s_tgt [n][head]
  __shared__ float  sh_al[VN][4][3];     // alphas [n][head][edge]

  const int b    = blockIdx.x;
  const int tid  = threadIdx.x;
  const int w    = tid >> 6;
  const int lane = tid & 63;
  const int l    = lane & 15;
  const int q    = lane >> 4;
  const int cb   = w * 64;
  const int colbase8 = (cb + l) * 8;

  // flat-epilogue indexing: f-quad + per-wave 16-node stripe
  const int fq  = (tid & 63) * 4;
  const int ns  = (tid >> 6) * 16;
  const int qhd = fq >> 6;

  __bf16* hb = bufA;   // current activations (MFMA A source)
  __bf16* ag = bufB;   // skip+bias staging / proj buffer

  if (tid < 128) sh_temb[tid] = d_temb[b * 128 + tid];
  __syncthreads();

  // ------------- h0 = [coords(2), pos(4), temb(128)], zero pad to 160 --------
  for (int idx = tid; idx < VN * 160; idx += 256) {
    int n = idx / 160, k = idx - n * 160;
    float v = 0.0f;
    if (k < 2) {
      v = x[b * 128 + 2 * n + k];
    } else if (k < 6) {
      float ph  = (float)n * 0.09817477042468103f;  // 2*pi/64
      float arg = (k < 4) ? ph : 2.0f * ph;
      v = ((k & 1) == 0) ? sinf(arg) : cosf(arg);
    } else if (k < 134) {
      v = sh_temb[k - 6];
    }
    hb[n * KPAD + k] = (__bf16)v;
  }
  __syncthreads();

  const int WOFFS[3]  = {OFF_W0, OFF_W1, OFF_W2};
  const int SOFFS[3]  = {OFF_SK0, OFF_SK1, OFF_SK2};
  const int SAOFFS[3] = {OFF_SA0, OFF_SA1, OFF_SA2};
  const float* Bs[3]  = {b0, b1, b2};

  // ---------------- GAT layers 0..2 (NH=4, FOUT=64, concat + elu) ------------
  for (int li = 0; li < 3; li++) {
    // ---- pass A: skip projection + bias -> ag (bf16, lane-owned) ----
    {
      f32x4 accS[4][4];
#pragma unroll
      for (int rt = 0; rt < 4; rt++)
#pragma unroll
        for (int ct = 0; ct < 4; ct++) accS[rt][ct] = (f32x4)0.0f;
      if (li == 0) mfma_mm<5>(WP + OFF_SK0,   accS, hb, l, q, colbase8);
      else         mfma_mm<8>(WP + SOFFS[li], accS, hb, l, q, colbase8);
      float b4[4];
#pragma unroll
      for (int ct = 0; ct < 4; ct++) b4[ct] = Bs[li][cb + ct * 16 + l];
#pragma unroll
      for (int rt = 0; rt < 4; rt++)
#pragma unroll
        for (int reg = 0; reg < 4; reg++) {
          int n = rt * 16 + q * 4 + reg;
#pragma unroll
          for (int ct = 0; ct < 4; ct++)
            ag[n * KPAD + cb + ct * 16 + l] = (__bf16)(accS[rt][ct][reg] + b4[ct]);
        }
    }

    // ---- pass B: main projection + score columns (all waves, uniform) ----
    f32x4 acc[4][4], acc_sc[4];
#pragma unroll
    for (int rt = 0; rt < 4; rt++) {
#pragma unroll
      for (int ct = 0; ct < 4; ct++) acc[rt][ct] = (f32x4)0.0f;
      acc_sc[rt] = (f32x4)0.0f;
    }
    if (li == 0) mfma_mm_sc<5>(WP + OFF_W0,    WP + OFF_SA0,    acc, acc_sc, hb, l, q, colbase8);
    else         mfma_mm_sc<8>(WP + WOFFS[li], WP + SAOFFS[li], acc, acc_sc, hb, l, q, colbase8);

    // scores -> LDS: col l<4 = s_src head l, col 4..7 = s_tgt (r10-proven)
    if (l < 8) {
#pragma unroll
      for (int rt = 0; rt < 4; rt++)
#pragma unroll
        for (int reg = 0; reg < 4; reg++) {
          int n = rt * 16 + q * 4 + reg;
          float v = acc_sc[rt][reg];
          if (l < 4) sh_ssp[n * 4 + l] = v;
          else       sh_stp[n * 4 + (l - 4)] = v;
        }
    }
    __syncthreads();   // all hb reads done (A+B); scores visible

    // proj dump: acc -> hb (bf16, lane-owned; h is dead now)
#pragma unroll
    for (int rt = 0; rt < 4; rt++)
#pragma unroll
      for (int reg = 0; reg < 4; reg++) {
        int n = rt * 16 + q * 4 + reg;
#pragma unroll
        for (int ct = 0; ct < 4; ct++)
          hb[n * KPAD + cb + ct * 16 + l] = (__bf16)acc[rt][ct][reg];
      }

    { // softmax over {prv,nxt,self}: thread per (node, head)
      int n = tid >> 2, hd = tid & 3;
      int prv = (n + 63) & 63, nxt = (n + 1) & 63;
      float stg = sh_stp[n * 4 + hd];
      float e0 = sh_ssp[prv * 4 + hd] + stg; e0 = (e0 < 0.0f) ? 0.2f * e0 : e0;
      float e1 = sh_ssp[nxt * 4 + hd] + stg; e1 = (e1 < 0.0f) ? 0.2f * e1 : e1;
      float e2 = sh_ssp[n * 4 + hd]   + stg; e2 = (e2 < 0.0f) ? 0.2f * e2 : e2;
      float mx = fmaxf(e0, fmaxf(e1, e2));
      float x0 = fexp(e0 - mx), x1 = fexp(e1 - mx), x2 = fexp(e2 - mx);
      float inv = frcp(x0 + x1 + x2 + 1e-16f);
      sh_al[n][hd][0] = x0 * inv;
      sh_al[n][hd][1] = x1 * inv;
      sh_al[n][hd][2] = x2 * inv;
    }
    __syncthreads();   // proj + alphas visible

    // ---- flat epilogue (4-feat quads): o = elu(gather(proj) + ag) ----
    {
      float pm[4], pc[4];
      { bf16x4 v = *(const bf16x4*)(hb + ((ns + 63) & 63) * KPAD + fq);
#pragma unroll
        for (int j = 0; j < 4; j++) pm[j] = (float)v[j]; }
      { bf16x4 v = *(const bf16x4*)(hb + ns * KPAD + fq);
#pragma unroll
        for (int j = 0; j < 4; j++) pc[j] = (float)v[j]; }
#pragma unroll 4
      for (int i = 0; i < 16; i++) {
        int n = ns + i;
        bf16x4 pnv = *(const bf16x4*)(hb + ((n + 1) & 63) * KPAD + fq);
        bf16x4 agv = *(const bf16x4*)(ag + n * KPAD + fq);
        float a0 = sh_al[n][qhd][0], a1 = sh_al[n][qhd][1], a2 = sh_al[n][qhd][2];
        bf16x4 ov;
#pragma unroll
        for (int j = 0; j < 4; j++) {
          float pn = (float)pnv[j];
          float o = a0 * pm[j] + a1 * pn + a2 * pc[j] + (float)agv[j];
          o = (o > 0.0f) ? o : (fexp(o) - 1.0f);
          ov[j] = (__bf16)o;
          pm[j] = pc[j]; pc[j] = pn;
        }
        *(bf16x4*)(ag + n * KPAD + fq) = ov;
      }
    }
    __syncthreads();   // new h (in ag) complete

    __bf16* tmp = hb; hb = ag; ag = tmp;   // ping-pong
  }

  // ---------------- GAT layer 3 (NH=1, FOUT=256, identity skip, no act) ------
  {
    f32x4 acc[4][4], acc_sc[4];
#pragma unroll
    for (int rt = 0; rt < 4; rt++) {
#pragma unroll
      for (int ct = 0; ct < 4; ct++) acc[rt][ct] = (f32x4)0.0f;
      acc_sc[rt] = (f32x4)0.0f;
    }
    mfma_mm_sc<8>(WP + OFF_W3, WP + OFF_SA3, acc, acc_sc, hb, l, q, colbase8);

    if (l < 2) {   // col 0 = s_src, col 1 = s_tgt
#pragma unroll
      for (int rt = 0; rt < 4; rt++)
#pragma unroll
        for (int reg = 0; reg < 4; reg++) {
          int n = rt * 16 + q * 4 + reg;
          float v = acc_sc[rt][reg];
          if (l == 0) sh_ssp[n * 4] = v;
          else        sh_stp[n * 4] = v;
        }
    }
    __syncthreads();

    // proj dump: acc -> ag (hb holds h, needed for residual)
#pragma unroll
    for (int rt = 0; rt < 4; rt++)
#pragma unroll
      for (int reg = 0; reg < 4; reg++) {
        int n = rt * 16 + q * 4 + reg;
#pragma unroll
        for (int ct = 0; ct < 4; ct++)
          ag[n * KPAD + cb + ct * 16 + l] = (__bf16)acc[rt][ct][reg];
      }

    if (tid < 64) {  // softmax, single head
      int n = tid;
      float ssn = sh_ssp[n * 4];
      float stn = sh_stp[n * 4];
      float ssp = __shfl(ssn, (n + 63) & 63, 64);
      float ssx = __shfl(ssn, (n + 1) & 63, 64);
      float e0 = ssp + stn; e0 = (e0 < 0.0f) ? 0.2f * e0 : e0;
      float e1 = ssx + stn; e1 = (e1 < 0.0f) ? 0.2f * e1 : e1;
      float e2 = ssn + stn; e2 = (e2 < 0.0f) ? 0.2f * e2 : e2;
      float mx = fmaxf(e0, fmaxf(e1, e2));
      float x0 = fexp(e0 - mx), x1 = fexp(e1 - mx), x2 = fexp(e2 - mx);
      float inv = frcp(x0 + x1 + x2 + 1e-16f);
      sh_al[n][0][0] = x0 * inv;
      sh_al[n][0][1] = x1 * inv;
      sh_al[n][0][2] = x2 * inv;
    }
    __syncthreads();

    { // flat epilogue (4-feat quads): o = gather(ag) + hb(residual) + b3 -> hb
      float b3r[4];
#pragma unroll
      for (int j = 0; j < 4; j++) b3r[j] = b3[fq + j];
      float pm[4], pc[4];
      { bf16x4 v = *(const bf16x4*)(ag + ((ns + 63) & 63) * KPAD + fq);
#pragma unroll
        for (int j = 0; j < 4; j++) pm[j] = (float)v[j]; }
      { bf16x4 v = *(const bf16x4*)(ag + ns * KPAD + fq);
#pragma unroll
        for (int j = 0; j < 4; j++) pc[j] = (float)v[j]; }
#pragma unroll 4
      for (int i = 0; i < 16; i++) {
        int n = ns + i;
        bf16x4 pnv = *(const bf16x4*)(ag + ((n + 1) & 63) * KPAD + fq);
        bf16x4 hrv = *(const bf16x4*)(hb + n * KPAD + fq);
        float a0 = sh_al[n][0][0], a1 = sh_al[n][0][1], a2 = sh_al[n][0][2];
        bf16x4 ov;
#pragma unroll
        for (int j = 0; j < 4; j++) {
          float pn = (float)pnv[j];
          float o = a0 * pm[j] + a1 * pn + a2 * pc[j] + (float)hrv[j] + b3r[j];
          ov[j] = (__bf16)o;
          pm[j] = pc[j]; pc[j] = pn;
        }
        *(bf16x4*)(hb + n * KPAD + fq) = ov;
      }
    }
    __syncthreads();
  }

  // ---------------- head MLP: silu(h@h1W+h1b), then h@h2W+h2b ----------------
  {
    f32x4 acc[4][4];
#pragma unroll
    for (int rt = 0; rt < 4; rt++)
#pragma unroll
      for (int ct = 0; ct < 4; ct++) acc[rt][ct] = (f32x4)0.0f;
    mfma_mm<8>(WP + OFF_H1W, acc, hb, l, q, colbase8);
    __syncthreads();

    float b4[4];
#pragma unroll
    for (int ct = 0; ct < 4; ct++) b4[ct] = h1b[cb + ct * 16 + l];
#pragma unroll
    for (int rt = 0; rt < 4; rt++)
#pragma unroll
      for (int reg = 0; reg < 4; reg++) {
        int n = rt * 16 + q * 4 + reg;
#pragma unroll
        for (int ct = 0; ct < 4; ct++) {
          float o = acc[rt][ct][reg] + b4[ct];
          o = o * frcp(1.0f + fexp(-o));   // silu
          hb[n * KPAD + cb + ct * 16 + l] = (__bf16)o;
        }
      }
    __syncthreads();

    { // final 256 -> 2, all 256 threads: split-K by 2 + pair combine
      int n = tid >> 2, c = (tid >> 1) & 1, half = tid & 1;
      const float* wrow = h2wt + c * 256 + half * 128;
      const __bf16* hrow = hb + n * KPAD + half * 128;
      float o = half ? 0.0f : h2b[c];
#pragma unroll 4
      for (int k8 = 0; k8 < 16; k8++) {
        bf16x8 hv = *(const bf16x8*)(hrow + k8 * 8);
        f32x4 w0 = *(const f32x4*)(wrow + k8 * 8);
        f32x4 w1 = *(const f32x4*)(wrow + k8 * 8 + 4);
#pragma unroll
        for (int j = 0; j < 4; j++) o = fmaf((float)hv[j], w0[j], o);
#pragma unroll
        for (int j = 0; j < 4; j++) o = fmaf((float)hv[4 + j], w1[j], o);
      }
      o += __shfl_xor(o, 1, 64);
      if (!half) out[b * 128 + 2 * n + c] = o;
    }
  }
}

extern "C" void kernel_launch(void* const* d_in, const int* in_sizes, int n_in,
                              void* d_out, int out_size, void* d_ws, size_t ws_size,
                              hipStream_t stream)
{
  auto fp = [&](int i) { return (const float*)d_in[i]; };
  __bf16* wp   = (__bf16*)d_ws;
  float* h2wt  = (float*)(wp + OFF_END);        // 512 fp32 (16B aligned)
  float* dtemb = h2wt + 512;                    // 2048*128 fp32

  setup_all<<<1200, 256, 0, stream>>>(fp(4), fp(20), fp(8), fp(21),
                                      fp(12), fp(22), fp(16), fp(23),
                                      fp(25),
                                      fp(5),  fp(6),  fp(9),  fp(10),
                                      fp(13), fp(14), fp(17), fp(18),
                                      (const int*)d_in[1], fp(2), fp(3),
                                      h2wt, dtemb, wp);

  gat_poly_kernel<<<2048, 256, 0, stream>>>(
      fp(0),
      fp(7), fp(11), fp(15), fp(19),   // b0..b3
      fp(24), fp(26),                  // h1b h2b
      wp, h2wt, dtemb,
      (float*)d_out);
}

// Round 18
// 357.545 us; speedup vs baseline: 1.5681x; 1.0306x over previous
//
#include <hip/hip_runtime.h>
#include <hip/hip_bf16.h>

#define VN    64
#define KPAD  264   // bf16 row stride: rows 16B-aligned (528B)

typedef __bf16 bf16x8 __attribute__((ext_vector_type(8)));
typedef __bf16 bf16x4 __attribute__((ext_vector_type(4)));
typedef float  f32x4  __attribute__((ext_vector_type(4)));

// fast transcendentals: v_exp_f32 / v_rcp_f32
__device__ __forceinline__ float fexp(float x) { return __expf(x); }
__device__ __forceinline__ float frcp(float x) { return __builtin_amdgcn_rcpf(x); }

// packed-weight bf16 element offsets in d_ws
#define OFF_W0   0
#define OFF_SK0  40960
#define OFF_W1   81920
#define OFF_SK1  147456
#define OFF_W2   212992
#define OFF_SK2  278528
#define OFF_W3   344064
#define OFF_H1W  409600
#define OFF_SA0  475136    // score cols layer0: 160 x 16
#define OFF_SA1  477696    // 256 x 16
#define OFF_SA2  481792
#define OFF_SA3  485888
#define OFF_END  489984    // bf16 elems; byte 979968 (16B aligned)

// packed-B column permutation: slot n holds source feature perm(n) so that
// MFMA tile ct, lane l outputs feature cb + 4*l + ct (contiguous per lane)
__device__ __forceinline__ int permcol(int n) {
  return (n & 0xC0) | (((n & 15) << 2) | ((n >> 4) & 3));
}

// ---- fused setup kernel (r17 structure + column interleave in pack) ----
__global__ void setup_all(const float* __restrict__ W0s, const float* __restrict__ sk0s,
                          const float* __restrict__ W1s, const float* __restrict__ sk1s,
                          const float* __restrict__ W2s, const float* __restrict__ sk2s,
                          const float* __restrict__ W3s, const float* __restrict__ h1Ws,
                          const float* __restrict__ h2W,
                          const float* __restrict__ as0, const float* __restrict__ at0,
                          const float* __restrict__ as1, const float* __restrict__ at1,
                          const float* __restrict__ as2, const float* __restrict__ at2,
                          const float* __restrict__ as3, const float* __restrict__ at3,
                          const int* __restrict__ t, const float* __restrict__ tW,
                          const float* __restrict__ tb,
                          float* __restrict__ h2wt, float* __restrict__ d_temb,
                          __bf16* __restrict__ wp)
{
  int blk = blockIdx.x, tid = threadIdx.x;
  if (blk < 116) {
    __shared__ float shw[16][257];
    const float* src; int fin, dstoff, s;
    if (blk < 20) {
      if (blk < 10) { src = W0s;  dstoff = OFF_W0;  s = blk; }
      else          { src = sk0s; dstoff = OFF_SK0; s = blk - 10; }
      fin = 134;
    } else {
      int r = (blk - 20) >> 4;
      s = (blk - 20) & 15;
      const float* srcs[6] = {W1s, sk1s, W2s, sk2s, W3s, h1Ws};
      const int    offs[6] = {OFF_W1, OFF_SK1, OFF_W2, OFF_SK2, OFF_W3, OFF_H1W};
      src = srcs[r]; dstoff = offs[r]; fin = 256;
    }
#pragma unroll
    for (int it = 0; it < 16; it++) {
      int elem = it * 256 + tid;
      int r = elem >> 8, n = elem & 255;
      int k = s * 16 + r;
      shw[r][n] = (k < fin) ? src[k * 256 + n] : 0.0f;
    }
    __syncthreads();
#pragma unroll
    for (int it = 0; it < 16; it++) {
      int lin = it * 256 + tid;
      int k7 = lin & 7, n = (lin >> 3) & 255, cl = lin >> 11;
      wp[dstoff + s * 4096 + lin] = (__bf16)shw[cl * 8 + k7][permcol(n)];
    }
  } else if (blk < 118) {
    int idx = (blk - 116) * 256 + tid;
    int c = idx >> 8, k = idx & 255;
    h2wt[idx] = h2W[k * 2 + c];
  } else if (blk < 176) {
    int idx = (blk - 118) * 256 + tid;   // 928 rows x 16 cols = 14848
    if (idx < 14848) {
      int gk = idx >> 4, c = idx & 15;
      int li, k, fin, dstoff;
      if (gk < 160)      { li = 0; k = gk;       fin = 134; dstoff = OFF_SA0; }
      else if (gk < 416) { li = 1; k = gk - 160; fin = 256; dstoff = OFF_SA1; }
      else if (gk < 672) { li = 2; k = gk - 416; fin = 256; dstoff = OFF_SA2; }
      else               { li = 3; k = gk - 672; fin = 256; dstoff = OFF_SA3; }
      float v = 0.0f;
      if (k < fin) {
        if (li < 3) {
          if (c < 8) {
            int hd = c & 3;
            const float* Wm = (li == 0) ? W0s : (li == 1) ? W1s : W2s;
            const float* a  = (c < 4) ? ((li == 0) ? as0 : (li == 1) ? as1 : as2)
                                      : ((li == 0) ? at0 : (li == 1) ? at1 : at2);
            for (int f = 0; f < 64; f++)
              v += Wm[k * 256 + hd * 64 + f] * a[hd * 64 + f];
          }
        } else {
          if (c < 2) {
            const float* a = (c == 0) ? as3 : at3;
            for (int f = 0; f < 256; f++)
              v += W3s[k * 256 + f] * a[f];
          }
        }
      }
      wp[dstoff + ((k >> 3) * 16 + c) * 8 + (k & 7)] = (__bf16)v;
    }
  } else {
    __shared__ float se[2][128];
    int half = tid >> 7, tt = tid & 127;
    int b = (blk - 176) * 2 + half;
    int fi = tt & 63;
    float fr = expf(-logf(10000.0f) * (float)fi / 63.0f);
    float te = (float)t[b] * fr;
    se[half][tt] = (tt < 64) ? sinf(te) : cosf(te);
    __syncthreads();
    float a = tb[tt];
    for (int k = 0; k < 128; k++)
      a = fmaf(se[half][k], tW[k * 128 + tt], a);
    d_temb[b * 128 + tt] = a * frcp(1.0f + fexp(-a));
  }
}

// single-B matmul: acc += A(64 x 32*KS from LDS) @ B(packed global)
template<int KS>
__device__ __forceinline__ void mfma_mm(const __bf16* __restrict__ Bp,
                                        f32x4 acc[4][4],
                                        const __bf16* __restrict__ shA,
                                        int l, int q, int colbase8)
{
#pragma unroll
  for (int s = 0; s < KS; s++) {
    bf16x8 af[4], bfr[4];
#pragma unroll
    for (int rt = 0; rt < 4; rt++)
      af[rt] = *(const bf16x8*)(shA + (rt * 16 + l) * KPAD + s * 32 + q * 8);
#pragma unroll
    for (int ct = 0; ct < 4; ct++)
      bfr[ct] = *(const bf16x8*)(Bp + (s * 4 + q) * 2048 + colbase8 + ct * 128);
#pragma unroll
    for (int rt = 0; rt < 4; rt++)
#pragma unroll
      for (int ct = 0; ct < 4; ct++)
        acc[rt][ct] = __builtin_amdgcn_mfma_f32_16x16x32_bf16(af[rt], bfr[ct], acc[rt][ct], 0, 0, 0);
  }
}

// matmul + score columns
template<int KS>
__device__ __forceinline__ void mfma_mm_sc(const __bf16* __restrict__ Bp,
                                           const __bf16* __restrict__ SAp,
                                           f32x4 acc[4][4], f32x4 acc_sc[4],
                                           const __bf16* __restrict__ shA,
                                           int l, int q, int colbase8)
{
#pragma unroll
  for (int s = 0; s < KS; s++) {
    bf16x8 af[4], bfr[4], bsc;
#pragma unroll
    for (int rt = 0; rt < 4; rt++)
      af[rt] = *(const bf16x8*)(shA + (rt * 16 + l) * KPAD + s * 32 + q * 8);
#pragma unroll
    for (int ct = 0; ct < 4; ct++)
      bfr[ct] = *(const bf16x8*)(Bp + (s * 4 + q) * 2048 + colbase8 + ct * 128);
    bsc = *(const bf16x8*)(SAp + (s * 4 + q) * 128 + l * 8);
#pragma unroll
    for (int rt = 0; rt < 4; rt++) {
#pragma unroll
      for (int ct = 0; ct < 4; ct++)
        acc[rt][ct] = __builtin_amdgcn_mfma_f32_16x16x32_bf16(af[rt], bfr[ct], acc[rt][ct], 0, 0, 0);
      acc_sc[rt] = __builtin_amdgcn_mfma_f32_16x16x32_bf16(af[rt], bsc, acc_sc[rt], 0, 0, 0);
    }
  }
}

__global__ __launch_bounds__(256, 2)
void gat_poly_kernel(const float* __restrict__ x,
                     const float* __restrict__ b0, const float* __restrict__ b1,
                     const float* __restrict__ b2, const float* __restrict__ b3,
                     const float* __restrict__ h1b, const float* __restrict__ h2b,
                     const __bf16* __restrict__ WP,
                     const float* __restrict__ h2wt,
                     const float* __restrict__ d_temb,
                     float* __restrict__ out)
{
  __shared__ __bf16 bufA[VN * KPAD];
  __shared__ __bf16 bufB[VN * KPAD];
  __shared__ float  sh_temb[128];
  __shared__ float  sh_ssp[VN * 4];      // s_src [n][head]
  __shared__ float  sh_stp[VN * 4];      // s_tgt [n][head]
  __shared__ float  sh_al[VN][4][3];     // alphas [n][head][edge]

  const int b    = blockIdx.x;
  const int tid  = threadIdx.x;
  const int w    = tid >> 6;
  const int lane = tid & 63;
  const int l    = lane & 15;
  const int q    = lane >> 4;
  const int cb   = w * 64;
  const int colbase8 = (cb + l) * 8;
  const int fb   = cb + 4 * l;           // this lane's contiguous 4-feature base

  // flat-epilogue indexing: 8-feat octet + 8-node stripe
  const int fo  = (tid & 31) * 8;
  const int no  = (tid >> 5) * 8;
  const int ohd = fo >> 6;

  __bf16* hb = bufA;   // current activations (MFMA A source)
  __bf16* ag = bufB;   // skip+bias staging / proj buffer

  if (tid < 128) sh_temb[tid] = d_temb[b * 128 + tid];
  __syncthreads();

  // ------------- h0 = [coords(2), pos(4), temb(128)], zero pad to 160 --------
  for (int idx = tid; idx < VN * 160; idx += 256) {
    int n = idx / 160, k = idx - n * 160;
    float v = 0.0f;
    if (k < 2) {
      v = x[b * 128 + 2 * n + k];
    } else if (k < 6) {
      float ph  = (float)n * 0.09817477042468103f;  // 2*pi/64
      float arg = (k < 4) ? ph : 2.0f * ph;
      v = ((k & 1) == 0) ? sinf(arg) : cosf(arg);
    } else if (k < 134) {
      v = sh_temb[k - 6];
    }
    hb[n * KPAD + k] = (__bf16)v;
  }
  __syncthreads();

  const int WOFFS[3]  = {OFF_W0, OFF_W1, OFF_W2};
  const int SOFFS[3]  = {OFF_SK0, OFF_SK1, OFF_SK2};
  const int SAOFFS[3] = {OFF_SA0, OFF_SA1, OFF_SA2};
  const float* Bs[3]  = {b0, b1, b2};

  // ---------------- GAT layers 0..2 (NH=4, FOUT=64, concat + elu) ------------
  for (int li = 0; li < 3; li++) {
    // ---- pass A: skip projection + bias -> ag (vectorized bf16x4 stores) ----
    {
      f32x4 accS[4][4];
#pragma unroll
      for (int rt = 0; rt < 4; rt++)
#pragma unroll
        for (int ct = 0; ct < 4; ct++) accS[rt][ct] = (f32x4)0.0f;
      if (li == 0) mfma_mm<5>(WP + OFF_SK0,   accS, hb, l, q, colbase8);
      else         mfma_mm<8>(WP + SOFFS[li], accS, hb, l, q, colbase8);
      float b4[4];
#pragma unroll
      for (int ct = 0; ct < 4; ct++) b4[ct] = Bs[li][fb + ct];
#pragma unroll
      for (int rt = 0; rt < 4; rt++)
#pragma unroll
        for (int reg = 0; reg < 4; reg++) {
          int n = rt * 16 + q * 4 + reg;
          bf16x4 ov;
#pragma unroll
          for (int ct = 0; ct < 4; ct++) ov[ct] = (__bf16)(accS[rt][ct][reg] + b4[ct]);
          *(bf16x4*)(ag + n * KPAD + fb) = ov;
        }
    }

    // ---- pass B: main projection + score columns (all waves, uniform) ----
    f32x4 acc[4][4], acc_sc[4];
#pragma unroll
    for (int rt = 0; rt < 4; rt++) {
#pragma unroll
      for (int ct = 0; ct < 4; ct++) acc[rt][ct] = (f32x4)0.0f;
      acc_sc[rt] = (f32x4)0.0f;
    }
    if (li == 0) mfma_mm_sc<5>(WP + OFF_W0,    WP + OFF_SA0,    acc, acc_sc, hb, l, q, colbase8);
    else         mfma_mm_sc<8>(WP + WOFFS[li], WP + SAOFFS[li], acc, acc_sc, hb, l, q, colbase8);

    // scores -> LDS: col l<4 = s_src head l, col 4..7 = s_tgt
    if (l < 8) {
#pragma unroll
      for (int rt = 0; rt < 4; rt++)
#pragma unroll
        for (int reg = 0; reg < 4; reg++) {
          int n = rt * 16 + q * 4 + reg;
          float v = acc_sc[rt][reg];
          if (l < 4) sh_ssp[n * 4 + l] = v;
          else       sh_stp[n * 4 + (l - 4)] = v;
        }
    }
    __syncthreads();   // all hb reads done (A+B); scores visible

    // proj dump: acc -> hb, vectorized (natural feature order)
#pragma unroll
    for (int rt = 0; rt < 4; rt++)
#pragma unroll
      for (int reg = 0; reg < 4; reg++) {
        int n = rt * 16 + q * 4 + reg;
        bf16x4 ov;
#pragma unroll
        for (int ct = 0; ct < 4; ct++) ov[ct] = (__bf16)acc[rt][ct][reg];
        *(bf16x4*)(hb + n * KPAD + fb) = ov;
      }

    { // softmax over {prv,nxt,self}: thread per (node, head)
      int n = tid >> 2, hd = tid & 3;
      int prv = (n + 63) & 63, nxt = (n + 1) & 63;
      float stg = sh_stp[n * 4 + hd];
      float e0 = sh_ssp[prv * 4 + hd] + stg; e0 = (e0 < 0.0f) ? 0.2f * e0 : e0;
      float e1 = sh_ssp[nxt * 4 + hd] + stg; e1 = (e1 < 0.0f) ? 0.2f * e1 : e1;
      float e2 = sh_ssp[n * 4 + hd]   + stg; e2 = (e2 < 0.0f) ? 0.2f * e2 : e2;
      float mx = fmaxf(e0, fmaxf(e1, e2));
      float x0 = fexp(e0 - mx), x1 = fexp(e1 - mx), x2 = fexp(e2 - mx);
      float inv = frcp(x0 + x1 + x2 + 1e-16f);
      sh_al[n][hd][0] = x0 * inv;
      sh_al[n][hd][1] = x1 * inv;
      sh_al[n][hd][2] = x2 * inv;
    }
    __syncthreads();   // proj + alphas visible

    // ---- flat epilogue (8-feat octets): o = elu(gather(proj) + ag) ----
    {
      float pm[8], pc[8];
      { bf16x8 v = *(const bf16x8*)(hb + ((no + 63) & 63) * KPAD + fo);
#pragma unroll
        for (int j = 0; j < 8; j++) pm[j] = (float)v[j]; }
      { bf16x8 v = *(const bf16x8*)(hb + no * KPAD + fo);
#pragma unroll
        for (int j = 0; j < 8; j++) pc[j] = (float)v[j]; }
#pragma unroll
      for (int i = 0; i < 8; i++) {
        int n = no + i;
        bf16x8 pnv = *(const bf16x8*)(hb + ((n + 1) & 63) * KPAD + fo);
        bf16x8 agv = *(const bf16x8*)(ag + n * KPAD + fo);
        float a0 = sh_al[n][ohd][0], a1 = sh_al[n][ohd][1], a2 = sh_al[n][ohd][2];
        bf16x8 ov;
#pragma unroll
        for (int j = 0; j < 8; j++) {
          float pn = (float)pnv[j];
          float o = a0 * pm[j] + a1 * pn + a2 * pc[j] + (float)agv[j];
          o = (o > 0.0f) ? o : (fexp(o) - 1.0f);
          ov[j] = (__bf16)o;
          pm[j] = pc[j]; pc[j] = pn;
        }
        *(bf16x8*)(ag + n * KPAD + fo) = ov;
      }
    }
    __syncthreads();   // new h (in ag) complete

    __bf16* tmp = hb; hb = ag; ag = tmp;   // ping-pong
  }

  // ---------------- GAT layer 3 (NH=1, FOUT=256, identity skip, no act) ------
  {
    f32x4 acc[4][4], acc_sc[4];
#pragma unroll
    for (int rt = 0; rt < 4; rt++) {
#pragma unroll
      for (int ct = 0; ct < 4; ct++) acc[rt][ct] = (f32x4)0.0f;
      acc_sc[rt] = (f32x4)0.0f;
    }
    mfma_mm_sc<8>(WP + OFF_W3, WP + OFF_SA3, acc, acc_sc, hb, l, q, colbase8);

    if (l < 2) {   // col 0 = s_src, col 1 = s_tgt
#pragma unroll
      for (int rt = 0; rt < 4; rt++)
#pragma unroll
        for (int reg = 0; reg < 4; reg++) {
          int n = rt * 16 + q * 4 + reg;
          float v = acc_sc[rt][reg];
          if (l == 0) sh_ssp[n * 4] = v;
          else        sh_stp[n * 4] = v;
        }
    }
    __syncthreads();

    // proj dump: acc -> ag, vectorized (hb holds h for the residual)
#pragma unroll
    for (int rt = 0; rt < 4; rt++)
#pragma unroll
      for (int reg = 0; reg < 4; reg++) {
        int n = rt * 16 + q * 4 + reg;
        bf16x4 ov;
#pragma unroll
        for (int ct = 0; ct < 4; ct++) ov[ct] = (__bf16)acc[rt][ct][reg];
        *(bf16x4*)(ag + n * KPAD + fb) = ov;
      }

    if (tid < 64) {  // softmax, single head
      int n = tid;
      float ssn = sh_ssp[n * 4];
      float stn = sh_stp[n * 4];
      float ssp = __shfl(ssn, (n + 63) & 63, 64);
      float ssx = __shfl(ssn, (n + 1) & 63, 64);
      float e0 = ssp + stn; e0 = (e0 < 0.0f) ? 0.2f * e0 : e0;
      float e1 = ssx + stn; e1 = (e1 < 0.0f) ? 0.2f * e1 : e1;
      float e2 = ssn + stn; e2 = (e2 < 0.0f) ? 0.2f * e2 : e2;
      float mx = fmaxf(e0, fmaxf(e1, e2));
      float x0 = fexp(e0 - mx), x1 = fexp(e1 - mx), x2 = fexp(e2 - mx);
      float inv = frcp(x0 + x1 + x2 + 1e-16f);
      sh_al[n][0][0] = x0 * inv;
      sh_al[n][0][1] = x1 * inv;
      sh_al[n][0][2] = x2 * inv;
    }
    __syncthreads();

    { // flat epilogue (8-feat octets): o = gather(ag) + hb(residual) + b3 -> hb
      float b3r[8];
#pragma unroll
      for (int j = 0; j < 8; j++) b3r[j] = b3[fo + j];
      float pm[8], pc[8];
      { bf16x8 v = *(const bf16x8*)(ag + ((no + 63) & 63) * KPAD + fo);
#pragma unroll
        for (int j = 0; j < 8; j++) pm[j] = (float)v[j]; }
      { bf16x8 v = *(const bf16x8*)(ag + no * KPAD + fo);
#pragma unroll
        for (int j = 0; j < 8; j++) pc[j] = (float)v[j]; }
#pragma unroll
      for (int i = 0; i < 8; i++) {
        int n = no + i;
        bf16x8 pnv = *(const bf16x8*)(ag + ((n + 1) & 63) * KPAD + fo);
        bf16x8 hrv = *(const bf16x8*)(hb + n * KPAD + fo);
        float a0 = sh_al[n][0][0], a1 = sh_al[n][0][1], a2 = sh_al[n][0][2];
        bf16x8 ov;
#pragma unroll
        for (int j = 0; j < 8; j++) {
          float pn = (float)pnv[j];
          float o = a0 * pm[j] + a1 * pn + a2 * pc[j] + (float)hrv[j] + b3r[j];
          ov[j] = (__bf16)o;
          pm[j] = pc[j]; pc[j] = pn;
        }
        *(bf16x8*)(hb + n * KPAD + fo) = ov;
      }
    }
    __syncthreads();
  }

  // ---------------- head MLP: silu(h@h1W+h1b), then h@h2W+h2b ----------------
  {
    f32x4 acc[4][4];
#pragma unroll
    for (int rt = 0; rt < 4; rt++)
#pragma unroll
      for (int ct = 0; ct < 4; ct++) acc[rt][ct] = (f32x4)0.0f;
    mfma_mm<8>(WP + OFF_H1W, acc, hb, l, q, colbase8);
    __syncthreads();

    float b4[4];
#pragma unroll
    for (int ct = 0; ct < 4; ct++) b4[ct] = h1b[fb + ct];
#pragma unroll
    for (int rt = 0; rt < 4; rt++)
#pragma unroll
      for (int reg = 0; reg < 4; reg++) {
        int n = rt * 16 + q * 4 + reg;
        bf16x4 ov;
#pragma unroll
        for (int ct = 0; ct < 4; ct++) {
          float o = acc[rt][ct][reg] + b4[ct];
          o = o * frcp(1.0f + fexp(-o));   // silu
          ov[ct] = (__bf16)o;
        }
        *(bf16x4*)(hb + n * KPAD + fb) = ov;
      }
    __syncthreads();

    { // final 256 -> 2, all 256 threads: split-K by 2 + pair combine
      int n = tid >> 2, c = (tid >> 1) & 1, half = tid & 1;
      const float* wrow = h2wt + c * 256 + half * 128;
      const __bf16* hrow = hb + n * KPAD + half * 128;
      float o = half ? 0.0f : h2b[c];
#pragma unroll 4
      for (int k8 = 0; k8 < 16; k8++) {
        bf16x8 hv = *(const bf16x8*)(hrow + k8 * 8);
        f32x4 w0 = *(const f32x4*)(wrow + k8 * 8);
        f32x4 w1 = *(const f32x4*)(wrow + k8 * 8 + 4);
#pragma unroll
        for (int j = 0; j < 4; j++) o = fmaf((float)hv[j], w0[j], o);
#pragma unroll
        for (int j = 0; j < 4; j++) o = fmaf((float)hv[4 + j], w1[j], o);
      }
      o += __shfl_xor(o, 1, 64);
      if (!half) out[b * 128 + 2 * n + c] = o;
    }
  }
}

extern "C" void kernel_launch(void* const* d_in, const int* in_sizes, int n_in,
                              void* d_out, int out_size, void* d_ws, size_t ws_size,
                              hipStream_t stream)
{
  auto fp = [&](int i) { return (const float*)d_in[i]; };
  __bf16* wp   = (__bf16*)d_ws;
  float* h2wt  = (float*)(wp + OFF_END);        // 512 fp32 (16B aligned)
  float* dtemb = h2wt + 512;                    // 2048*128 fp32

  setup_all<<<1200, 256, 0, stream>>>(fp(4), fp(20), fp(8), fp(21),
                                      fp(12), fp(22), fp(16), fp(23),
                                      fp(25),
                                      fp(5),  fp(6),  fp(9),  fp(10),
                                      fp(13), fp(14), fp(17), fp(18),
                                      (const int*)d_in[1], fp(2), fp(3),
                                      h2wt, dtemb, wp);

  gat_poly_kernel<<<2048, 256, 0, stream>>>(
      fp(0),
      fp(7), fp(11), fp(15), fp(19),   // b0..b3
      fp(24), fp(26),                  // h1b h2b
      wp, h2wt, dtemb,
      (float*)d_out);
}